// Round 10
// baseline (435.891 us; speedup 1.0000x reference)
//
#include <hip/hip_runtime.h>
#include <hip/hip_bf16.h>
#include <cstdint>
#include <cstddef>

// ---------------- types ----------------
typedef __attribute__((ext_vector_type(8))) short bf16x8;
typedef __attribute__((ext_vector_type(4))) float f32x4;

#define HDIM 1024
#define IDIM 2048
#define TTOK 4096
#define NEXP 8
#define ROWS_PAD 14336          // 256-padded routed (<=10240) + shared 4096
#define MT_MAX 64               // max 256-row m-tiles: <=40 routed + 16 shared
#define EXP_W_ELEMS 2097152ull  // 2048*1024 elems per weight matrix per expert

// ---------------- workspace layout (bytes) ----------------
#define OFF_WG   0ull
#define OFF_WU   (OFF_WG + 9ull * EXP_W_ELEMS * 2ull)
#define OFF_WD   (OFF_WU + 9ull * EXP_W_ELEMS * 2ull)
#define OFF_HF   (OFF_WD + 9ull * EXP_W_ELEMS * 2ull)            // [4096][1024] bf16
#define OFF_P    (OFF_HF + 4096ull * 1024ull * 2ull)             // [ROWS_PAD][2048] bf16
#define OFF_SLOT (OFF_P  + (size_t)ROWS_PAD * 2048ull * 2ull)    // [ROWS_PAD][1024] bf16
#define OFF_TOPI (OFF_SLOT + (size_t)ROWS_PAD * 1024ull * 2ull)  // [8192] int
#define OFF_TOPW (OFF_TOPI + 8192ull * 4ull)                     // [8192] f32
#define OFF_META (OFF_TOPW + 8192ull * 4ull)                     // 4096B ints/floats, see below
#define OFF_LTOK (OFF_META + 4096ull)                            // [ROWS_PAD] int
#define OFF_LW   (OFF_LTOK + (size_t)ROWS_PAD * 4ull)            // [ROWS_PAD] f32
#define OFF_ROWS (OFF_LW + (size_t)ROWS_PAD * 4ull)              // [8192] int

// meta (ints): [0..8]=cnt (router atomics), [16..24]=256-padded base,
//              [32..40]=cursor, [48]=ntiles256, [64..127]=tile->expert,
//              [128..191]=tile->row0, floats at [208..217]=aux sums
//              (pe[8], z, ent). META+LTOK+LW zeroed by hipMemsetAsync.

#define VM_WAIT(n) asm volatile("s_waitcnt vmcnt(" #n ")" ::: "memory")
#define SBAR __builtin_amdgcn_s_barrier()
#define FENCE __builtin_amdgcn_sched_barrier(0)
#define PRIO_HI __builtin_amdgcn_s_setprio(1)
#define PRIO_LO __builtin_amdgcn_s_setprio(0)

__device__ __forceinline__ float clamp500(float v) {
  return fminf(fmaxf(v, -500.f), 500.f);
}

__device__ __forceinline__ unsigned short f2bf(float f) {
  unsigned int u = __float_as_uint(f);
  u += 0x7FFFu + ((u >> 16) & 1u);  // RNE; inputs always finite here
  return (unsigned short)(u >> 16);
}

__device__ __forceinline__ float bf2f(unsigned short u) {
  return __uint_as_float((unsigned)u << 16);
}

// async global->LDS, 16B per lane. LDS dest must be wave-uniform base + lane*16.
__device__ __forceinline__ void stage16(const unsigned short* g, unsigned short* l) {
  __builtin_amdgcn_global_load_lds(
      (const __attribute__((address_space(1))) void*)g,
      (__attribute__((address_space(3))) void*)l, 16, 0, 0);
}

__device__ __forceinline__ f32x4 mfma16(bf16x8 a, bf16x8 b, f32x4 c) {
  return __builtin_amdgcn_mfma_f32_16x16x32_bf16(a, b, c, 0, 0, 0);
}

// ---------------- merged router + weight-conversion kernel ----------------
// blocks [0,1024): one wave per token -> LN, logits, softmax, top2; per-block
// LDS-combined aux partial sums via atomics (counts int = order-invariant).
// blocks [1024,3072): grid-stride fp32->bf16 convert of all 6 weight tensors.
#define CVT_BLKS 2048
#define E4 (8ull * EXP_W_ELEMS / 4ull)   // float4s per big matrix (8 experts)
#define S4 (EXP_W_ELEMS / 4ull)          // float4s per shared matrix
__global__ __launch_bounds__(256) void router_cvt_kernel(
    const float* __restrict__ x, const float* __restrict__ lnw,
    const float* __restrict__ lnb, const float* __restrict__ rw,
    const float* __restrict__ wg_f, const float* __restrict__ wu_f,
    const float* __restrict__ wd_f, const float* __restrict__ swg_f,
    const float* __restrict__ swu_f, const float* __restrict__ swd_f,
    unsigned short* __restrict__ wgb, unsigned short* __restrict__ wub,
    unsigned short* __restrict__ wdb,
    unsigned short* __restrict__ hf, int* __restrict__ top_i,
    float* __restrict__ top_w, int* __restrict__ meta) {
  if (blockIdx.x >= 1024) {
    // ---- cvt role ----
    size_t i = (size_t)(blockIdx.x - 1024) * 256 + threadIdx.x;
    const size_t stride = (size_t)CVT_BLKS * 256;
    const size_t n4 = 3 * (E4 + S4);
    for (; i < n4; i += stride) {
      size_t j = i;
      const float* src;
      unsigned short* dst;
      if (j < E4) { src = wg_f; dst = wgb; }
      else { j -= E4;
        if (j < S4) { src = swg_f; dst = wgb + 8 * EXP_W_ELEMS; }
        else { j -= S4;
          if (j < E4) { src = wu_f; dst = wub; }
          else { j -= E4;
            if (j < S4) { src = swu_f; dst = wub + 8 * EXP_W_ELEMS; }
            else { j -= S4;
              if (j < E4) { src = wd_f; dst = wdb; }
              else { j -= E4; src = swd_f; dst = wdb + 8 * EXP_W_ELEMS; }
            }
          }
        }
      }
      float4 f = ((const float4*)src)[j];
      uint2 pk;
      pk.x = (unsigned)f2bf(f.x) | ((unsigned)f2bf(f.y) << 16);
      pk.y = (unsigned)f2bf(f.z) | ((unsigned)f2bf(f.w) << 16);
      ((uint2*)dst)[j] = pk;
    }
    return;
  }
  // ---- router role ----
  __shared__ float sred[4][10];
  int wv = threadIdx.x >> 6, lane = threadIdx.x & 63;
  int t = blockIdx.x * 4 + wv;
  const float4* xr = (const float4*)(x + (size_t)t * HDIM);
  float4 v[4];
  float s = 0.f;
#pragma unroll
  for (int j = 0; j < 4; ++j) {
    float4 f = xr[j * 64 + lane];
    f.x = clamp500(f.x); f.y = clamp500(f.y);
    f.z = clamp500(f.z); f.w = clamp500(f.w);
    v[j] = f;
    ushort4 hh;
    hh.x = f2bf(f.x); hh.y = f2bf(f.y); hh.z = f2bf(f.z); hh.w = f2bf(f.w);
    ((ushort4*)hf)[(size_t)t * 256 + j * 64 + lane] = hh;
    s += f.x + f.y + f.z + f.w;
  }
#pragma unroll
  for (int m = 32; m; m >>= 1) s += __shfl_xor(s, m);
  float mu = s * (1.f / HDIM);
  float s2 = 0.f;
#pragma unroll
  for (int j = 0; j < 4; ++j) {
    float4 d = v[j];
    d.x -= mu; d.y -= mu; d.z -= mu; d.w -= mu;
    s2 += d.x * d.x + d.y * d.y + d.z * d.z + d.w * d.w;
  }
#pragma unroll
  for (int m = 32; m; m >>= 1) s2 += __shfl_xor(s2, m);
  float rstd = rsqrtf(s2 * (1.f / HDIM) + 1e-5f);
  float acc[8];
#pragma unroll
  for (int e = 0; e < 8; ++e) acc[e] = 0.f;
#pragma unroll
  for (int j = 0; j < 4; ++j) {
    float4 w = ((const float4*)lnw)[j * 64 + lane];
    float4 b = ((const float4*)lnb)[j * 64 + lane];
    float4 hn;
    hn.x = fminf(fmaxf((v[j].x - mu) * rstd * w.x + b.x, -50.f), 50.f);
    hn.y = fminf(fmaxf((v[j].y - mu) * rstd * w.y + b.y, -50.f), 50.f);
    hn.z = fminf(fmaxf((v[j].z - mu) * rstd * w.z + b.z, -50.f), 50.f);
    hn.w = fminf(fmaxf((v[j].w - mu) * rstd * w.w + b.w, -50.f), 50.f);
#pragma unroll
    for (int e = 0; e < 8; ++e) {
      float4 r = ((const float4*)(rw + e * HDIM))[j * 64 + lane];
      acc[e] += hn.x * r.x + hn.y * r.y + hn.z * r.z + hn.w * r.w;
    }
  }
#pragma unroll
  for (int e = 0; e < 8; ++e) {
    float a = acc[e];
#pragma unroll
    for (int m = 32; m; m >>= 1) a += __shfl_xor(a, m);
    acc[e] = a;
  }
  if (lane == 0) {
    float lg[8], mx = -1e30f;
#pragma unroll
    for (int e = 0; e < 8; ++e) {
      float l = fminf(fmaxf(acc[e], -10.f), 10.f);
      lg[e] = l;
      mx = fmaxf(mx, l);
    }
    float se = 0.f;
    float ex[8];
#pragma unroll
    for (int e = 0; e < 8; ++e) { ex[e] = expf(lg[e] - mx); se += ex[e]; }
    float inv = 1.f / se;
    float pr[8];
#pragma unroll
    for (int e = 0; e < 8; ++e) {
      float p = ex[e] * inv;
      pr[e] = fminf(fmaxf(p, 1e-4f), 1.f);
      sred[wv][e] = pr[e];
    }
    int i0 = 0; float v0 = pr[0];
#pragma unroll
    for (int e = 1; e < 8; ++e) if (pr[e] > v0) { v0 = pr[e]; i0 = e; }
    int i1 = -1; float v1 = -1.f;
#pragma unroll
    for (int e = 0; e < 8; ++e) if (e != i0 && pr[e] > v1) { v1 = pr[e]; i1 = e; }
    float dsum = fmaxf(v0 + v1, 1e-4f);
    top_i[2 * t] = i0; top_i[2 * t + 1] = i1;
    top_w[2 * t] = v0 / dsum; top_w[2 * t + 1] = v1 / dsum;
    atomicAdd(&meta[i0], 1);
    atomicAdd(&meta[i1], 1);
    float lse = mx + logf(se);
    sred[wv][8] = lse * lse;
    float ent = 0.f;
#pragma unroll
    for (int e = 0; e < 8; ++e) {
      float ps = fminf(fmaxf(pr[e], 1e-4f), 1.f - 1e-4f);
      ent -= ps * logf(ps);
    }
    sred[wv][9] = ent;
  }
  __syncthreads();
  if (threadIdx.x < 10) {
    float sm = sred[0][threadIdx.x] + sred[1][threadIdx.x] +
               sred[2][threadIdx.x] + sred[3][threadIdx.x];
    atomicAdd((float*)(meta + 208) + threadIdx.x, sm);
  }
}

// ---------------- aux loss + 256-padded tile map (single wave, tiny) ----------------
__global__ __launch_bounds__(64) void aux_kernel(
    int* __restrict__ meta, float* __restrict__ aux_out) {
  if (threadIdx.x != 0) return;
  const float* faux = (const float*)(meta + 208);
  float lb = 0.f, usage = 0.f;
  int cnt[8];
  for (int e = 0; e < 8; ++e) {
    cnt[e] = meta[e];
    float tpe = (float)cnt[e] / 8192.f;
    float avg = faux[e] / 4096.f;
    lb += tpe * avg;
    usage += (tpe > 0.01f) ? 1.f : 0.f;
  }
  lb *= 8.f;
  float z_loss = (faux[8] / 4096.f) * 0.001f;
  float ent_loss = fmaxf(logf(8.f) - faux[9] / 4096.f, 0.f) * 0.01f;
  float util = (1.f - usage / 8.f) * 0.1f;
  *aux_out = fminf(fmaxf(lb + z_loss + ent_loss + util, 0.f), 10.f);
  // 256-padded tile map
  int base = 0, tct = 0;
  for (int e = 0; e < 8; ++e) {
    meta[16 + e] = base;
    int nt = (cnt[e] + 255) >> 8;
    for (int i = 0; i < nt; ++i) { meta[64 + tct] = e; meta[128 + tct] = base + i * 256; ++tct; }
    base += nt * 256;
  }
  meta[8] = TTOK;           // shared "expert"
  meta[16 + 8] = base;      // shared padded base
  for (int i = 0; i < 16; ++i) { meta[64 + tct] = 8; meta[128 + tct] = base + i * 256; ++tct; }
  meta[48] = tct;
}

// ---------------- scatter tokens into per-expert padded lists ----------------
// (pad entries already zeroed by the launch-time memset: ltok=0, lw=0.0f)
__global__ __launch_bounds__(256) void scatter_kernel(
    const int* __restrict__ top_i, const float* __restrict__ top_w,
    int* __restrict__ meta, int* __restrict__ ltok, float* __restrict__ lw,
    int* __restrict__ rowslot) {
  int s = blockIdx.x * 256 + threadIdx.x;
  if (s < 8192) {
    int e = top_i[s];
    int pos = atomicAdd(&meta[32 + e], 1);
    int idx = meta[16 + e] + pos;
    ltok[idx] = s >> 1;
    lw[idx] = top_w[s];
    rowslot[s] = idx;
  }
  if (s < TTOK) {  // identity list for shared expert
    int sb = meta[16 + 8];
    ltok[sb + s] = s;
    lw[sb + s] = 1.f;
  }
}

// ---------------- GEMM1: P = clamp(silu(clamp(A*Wg^T)) * clamp(A*Wu^T)) ----------------
// BM=256, BN=128 (G and U), BK=64, 8 waves (2x4). All operands bf16 via
// global_load_lds. Pipelined: 8 stages for buf nxt at iter top, vmcnt(8)
// waits only the previous iter's loads, 2 barriers/iter. (Proven R4/R8 structure.)
__global__ __launch_bounds__(512, 1) void gemm1_kernel(
    const unsigned short* __restrict__ hf,
    const unsigned short* __restrict__ wg_all,
    const unsigned short* __restrict__ wu_all,
    unsigned short* __restrict__ P,
    const int* __restrict__ meta, const int* __restrict__ ltok) {
  int mt = blockIdx.y, nt = blockIdx.x;
  if (mt >= meta[48]) return;
  int ex = meta[64 + mt];
  int r0 = meta[128 + mt];
  extern __shared__ unsigned short lds[];
  unsigned short* sA = lds;          // 2 x 16384 elems (256x64)
  unsigned short* sG = lds + 32768;  // 2 x 8192  (128x64)
  unsigned short* sU = lds + 49152;  // 2 x 8192
  int tid = threadIdx.x, lane = tid & 63, wv = tid >> 6;
  int wr = wv >> 2, wc = wv & 3;
  int l15 = lane & 15, l4 = lane >> 4;
  int srow = tid >> 3;              // staging row within a 64-row issue
  int gch = (tid & 7) ^ (srow & 7); // inverse-swizzled source 16B chunk
  int ldst = tid * 8;               // linear LDS dest elems within an issue
  const unsigned short* wg = wg_all + (size_t)ex * EXP_W_ELEMS;
  const unsigned short* wu = wu_all + (size_t)ex * EXP_W_ELEMS;
  int n0 = nt * 128;
  const unsigned short* srcA[4];
#pragma unroll
  for (int i = 0; i < 4; ++i) {
    int tok = ltok[r0 + i * 64 + srow];
    srcA[i] = hf + (size_t)tok * HDIM + gch * 8;
  }
  const unsigned short* srcG[2];
  const unsigned short* srcU[2];
#pragma unroll
  for (int i = 0; i < 2; ++i) {
    srcG[i] = wg + (size_t)(n0 + i * 64 + srow) * HDIM + gch * 8;
    srcU[i] = wu + (size_t)(n0 + i * 64 + srow) * HDIM + gch * 8;
  }
  // swizzled ds_read chunk per kk (row&7 == lane&7 for all frag rows)
  int ch0 = (0 + l4) ^ (lane & 7);
  int ch1 = (4 + l4) ^ (lane & 7);
  int baseA = (wr * 128 + l15) * 64;
  int baseG = (wc * 32 + l15) * 64;

  f32x4 zero = {0.f, 0.f, 0.f, 0.f};
  f32x4 accg[8][2], accu[8][2];
#pragma unroll
  for (int m = 0; m < 8; ++m)
#pragma unroll
    for (int n = 0; n < 2; ++n) { accg[m][n] = zero; accu[m][n] = zero; }

  // prologue: stage K-step 0 into buf0 (no wait here; t=0 top waits)
#pragma unroll
  for (int i = 0; i < 4; ++i) stage16(srcA[i], &sA[i * 4096 + ldst]);
#pragma unroll
  for (int i = 0; i < 2; ++i) stage16(srcG[i], &sG[i * 4096 + ldst]);
#pragma unroll
  for (int i = 0; i < 2; ++i) stage16(srcU[i], &sU[i * 4096 + ldst]);

  for (int t = 0; t < 16; ++t) {
    int cur = t & 1, nxt = cur ^ 1;
    int cbA = cur * 16384, cbG = cur * 8192;
    int nbA = nxt * 16384, nbG = nxt * 8192;
    if (t < 15) {
      int k1 = (t + 1) * 64;
      stage16(srcA[0] + k1, &sA[nbA + 0 * 4096 + ldst]);
      stage16(srcA[1] + k1, &sA[nbA + 1 * 4096 + ldst]);
      stage16(srcA[2] + k1, &sA[nbA + 2 * 4096 + ldst]);
      stage16(srcA[3] + k1, &sA[nbA + 3 * 4096 + ldst]);
      stage16(srcG[0] + k1, &sG[nbG + 0 * 4096 + ldst]);
      stage16(srcG[1] + k1, &sG[nbG + 1 * 4096 + ldst]);
      stage16(srcU[0] + k1, &sU[nbG + 0 * 4096 + ldst]);
      stage16(srcU[1] + k1, &sU[nbG + 1 * 4096 + ldst]);
      VM_WAIT(8);   // previous iter's 8 (buf cur) landed; these 8 stay in flight
    } else {
      VM_WAIT(0);
    }
    SBAR; FENCE;    // all waves' cur stages landed
    bf16x8 af0[8], af1[8], g0[2], g1[2], u0[2], u1[2];
    // ---- kk0 ----
#pragma unroll
    for (int m = 0; m < 8; ++m)
      af0[m] = *(const bf16x8*)&sA[cbA + baseA + m * 1024 + ch0 * 8];
#pragma unroll
    for (int n = 0; n < 2; ++n)
      g0[n] = *(const bf16x8*)&sG[cbG + baseG + n * 1024 + ch0 * 8];
    PRIO_HI;
#pragma unroll
    for (int m = 0; m < 8; ++m)
#pragma unroll
      for (int n = 0; n < 2; ++n)
        accg[m][n] = mfma16(af0[m], g0[n], accg[m][n]);
    PRIO_LO;
#pragma unroll
    for (int n = 0; n < 2; ++n)
      u0[n] = *(const bf16x8*)&sU[cbG + baseG + n * 1024 + ch0 * 8];
    PRIO_HI;
#pragma unroll
    for (int m = 0; m < 8; ++m)
#pragma unroll
      for (int n = 0; n < 2; ++n)
        accu[m][n] = mfma16(af0[m], u0[n], accu[m][n]);
    PRIO_LO;
    // ---- kk1 ----
#pragma unroll
    for (int m = 0; m < 8; ++m)
      af1[m] = *(const bf16x8*)&sA[cbA + baseA + m * 1024 + ch1 * 8];
#pragma unroll
    for (int n = 0; n < 2; ++n)
      g1[n] = *(const bf16x8*)&sG[cbG + baseG + n * 1024 + ch1 * 8];
    PRIO_HI;
#pragma unroll
    for (int m = 0; m < 8; ++m)
#pragma unroll
      for (int n = 0; n < 2; ++n)
        accg[m][n] = mfma16(af1[m], g1[n], accg[m][n]);
    PRIO_LO;
#pragma unroll
    for (int n = 0; n < 2; ++n)
      u1[n] = *(const bf16x8*)&sU[cbG + baseG + n * 1024 + ch1 * 8];
    PRIO_HI;
#pragma unroll
    for (int m = 0; m < 8; ++m)
#pragma unroll
      for (int n = 0; n < 2; ++n)
        accu[m][n] = mfma16(af1[m], u1[n], accu[m][n]);
    PRIO_LO;
    FENCE; SBAR;    // all waves done reading cur before t+1 overwrites it
  }
  // epilogue: SwiGLU, write bf16 P (padded rows junk, never read)
  int rbase = r0 + wr * 128 + l4 * 4;
  int cbase = n0 + wc * 32 + l15;
#pragma unroll
  for (int m = 0; m < 8; ++m) {
#pragma unroll
    for (int r = 0; r < 4; ++r) {
      size_t prow = (size_t)(rbase + m * 16 + r) * IDIM;
#pragma unroll
      for (int n = 0; n < 2; ++n) {
        float g = clamp500(accg[m][n][r]);
        float u = clamp500(accu[m][n][r]);
        float sl = g / (1.f + __expf(-g));
        float p = clamp500(sl * u);
        P[prow + cbase + n * 16] = f2bf(p);
      }
    }
  }
}

// ---------------- GEMM2: slot = weight * clamp(P*Wd^T)  (shared: clamp(clamp(.)*sig)) ----------------
// BM=128, BN=128, BK=64, 4 waves (2x2), 64KB LDS -> 2 blocks/CU for
// cross-block latency hiding. Grid x = HDIM/128 = 8 (NOT 16 — R9 bug).
__global__ __launch_bounds__(256) void gemm2_kernel(
    const unsigned short* __restrict__ P,
    const unsigned short* __restrict__ wd_all,
    unsigned short* __restrict__ slot,
    const int* __restrict__ meta, const float* __restrict__ lw,
    const float* __restrict__ sgate) {
  int mt2 = blockIdx.y, nt = blockIdx.x;
  int tile = mt2 >> 1;
  if (tile >= meta[48]) return;
  int ex = meta[64 + tile];
  int r0 = meta[128 + tile] + (mt2 & 1) * 128;
  extern __shared__ unsigned short lds[];
  unsigned short* sA = lds;          // 2 x 8192 (128x64)
  unsigned short* sB = lds + 16384;  // 2 x 8192 (128x64)
  int tid = threadIdx.x, lane = tid & 63, wv = tid >> 6;
  int wr = wv >> 1, wc = wv & 1;
  int l15 = lane & 15, l4 = lane >> 4;
  int srow = tid >> 3;              // staging row within a 32-row issue
  int gch = (tid & 7) ^ (srow & 7);
  int ldst = tid * 8;               // 2048 elems per issue
  const unsigned short* wd = wd_all + (size_t)ex * EXP_W_ELEMS;
  int n0 = nt * 128;
  const unsigned short* srcA[4];
  const unsigned short* srcB[4];
#pragma unroll
  for (int i = 0; i < 4; ++i) {
    srcA[i] = P + (size_t)(r0 + i * 32 + srow) * IDIM + gch * 8;
    srcB[i] = wd + (size_t)(n0 + i * 32 + srow) * IDIM + gch * 8;
  }
  int ch0 = (0 + l4) ^ (lane & 7);
  int ch1 = (4 + l4) ^ (lane & 7);
  int baseA = (wr * 64 + l15) * 64;
  int baseB = (wc * 64 + l15) * 64;

  f32x4 zero = {0.f, 0.f, 0.f, 0.f};
  f32x4 acc[4][4];
#pragma unroll
  for (int m = 0; m < 4; ++m)
#pragma unroll
    for (int n = 0; n < 4; ++n) acc[m][n] = zero;

  // prologue
#pragma unroll
  for (int i = 0; i < 4; ++i) stage16(srcA[i], &sA[i * 2048 + ldst]);
#pragma unroll
  for (int i = 0; i < 4; ++i) stage16(srcB[i], &sB[i * 2048 + ldst]);

  for (int t = 0; t < 32; ++t) {
    int cur = t & 1, nxt = cur ^ 1;
    int cb = cur * 8192, nb = nxt * 8192;
    if (t < 31) {
      int k1 = (t + 1) * 64;
      stage16(srcA[0] + k1, &sA[nb + 0 * 2048 + ldst]);
      stage16(srcA[1] + k1, &sA[nb + 1 * 2048 + ldst]);
      stage16(srcA[2] + k1, &sA[nb + 2 * 2048 + ldst]);
      stage16(srcA[3] + k1, &sA[nb + 3 * 2048 + ldst]);
      stage16(srcB[0] + k1, &sB[nb + 0 * 2048 + ldst]);
      stage16(srcB[1] + k1, &sB[nb + 1 * 2048 + ldst]);
      stage16(srcB[2] + k1, &sB[nb + 2 * 2048 + ldst]);
      stage16(srcB[3] + k1, &sB[nb + 3 * 2048 + ldst]);
      VM_WAIT(8);
    } else {
      VM_WAIT(0);
    }
    SBAR; FENCE;
    bf16x8 af0[4], af1[4], b0[4], b1[4];
    // ---- kk0 ----
#pragma unroll
    for (int m = 0; m < 4; ++m)
      af0[m] = *(const bf16x8*)&sA[cb + baseA + m * 1024 + ch0 * 8];
#pragma unroll
    for (int n = 0; n < 4; ++n)
      b0[n] = *(const bf16x8*)&sB[cb + baseB + n * 1024 + ch0 * 8];
    PRIO_HI;
#pragma unroll
    for (int m = 0; m < 4; ++m)
#pragma unroll
      for (int n = 0; n < 4; ++n)
        acc[m][n] = mfma16(af0[m], b0[n], acc[m][n]);
    PRIO_LO;
    // ---- kk1 ----
#pragma unroll
    for (int m = 0; m < 4; ++m)
      af1[m] = *(const bf16x8*)&sA[cb + baseA + m * 1024 + ch1 * 8];
#pragma unroll
    for (int n = 0; n < 4; ++n)
      b1[n] = *(const bf16x8*)&sB[cb + baseB + n * 1024 + ch1 * 8];
    PRIO_HI;
#pragma unroll
    for (int m = 0; m < 4; ++m)
#pragma unroll
      for (int n = 0; n < 4; ++n)
        acc[m][n] = mfma16(af1[m], b1[n], acc[m][n]);
    PRIO_LO;
    FENCE; SBAR;
  }
  float gsig = 1.f / (1.f + __expf(-sgate[0]));
  int rbase = r0 + wr * 64 + l4 * 4;
  int cbase = n0 + wc * 64 + l15;
#pragma unroll
  for (int m = 0; m < 4; ++m) {
#pragma unroll
    for (int r = 0; r < 4; ++r) {
      int row = rbase + m * 16 + r;
      float wgt = (ex == 8) ? 1.f : lw[row];
      size_t srow_o = (size_t)row * HDIM;
#pragma unroll
      for (int n = 0; n < 4; ++n) {
        float o = clamp500(acc[m][n][r]);
        float val = (ex == 8) ? clamp500(o * gsig) : wgt * o;
        slot[srow_o + cbase + n * 16] = f2bf(val);
      }
    }
  }
}

// ---------------- combine: final = clamp(slot0 + slot1 + shared) ----------------
__global__ __launch_bounds__(256) void combine_kernel(
    const unsigned short* __restrict__ slot, const int* __restrict__ rowslot,
    const int* __restrict__ meta, float* __restrict__ out) {
  int i = blockIdx.x * 256 + threadIdx.x;  // 4-elem group index
  int t = i >> 8;
  int c = (i & 255) * 4;
  int sb = meta[16 + 8];
  int r0 = rowslot[2 * t], r1 = rowslot[2 * t + 1];
  ushort4 va = *(const ushort4*)(slot + (size_t)r0 * HDIM + c);
  ushort4 vb = *(const ushort4*)(slot + (size_t)r1 * HDIM + c);
  ushort4 vs = *(const ushort4*)(slot + (size_t)(sb + t) * HDIM + c);
  float4 o;
  o.x = clamp500(bf2f(va.x) + bf2f(vb.x) + bf2f(vs.x));
  o.y = clamp500(bf2f(va.y) + bf2f(vb.y) + bf2f(vs.y));
  o.z = clamp500(bf2f(va.z) + bf2f(vb.z) + bf2f(vs.z));
  o.w = clamp500(bf2f(va.w) + bf2f(vb.w) + bf2f(vs.w));
  *(float4*)(out + (size_t)t * HDIM + c) = o;
}

// ---------------- launch ----------------
extern "C" void kernel_launch(void* const* d_in, const int* in_sizes, int n_in,
                              void* d_out, int out_size, void* d_ws, size_t ws_size,
                              hipStream_t stream) {
  const float* x     = (const float*)d_in[0];
  const float* lnw   = (const float*)d_in[1];
  const float* lnb   = (const float*)d_in[2];
  const float* rw    = (const float*)d_in[3];
  const float* wg_f  = (const float*)d_in[4];
  const float* wu_f  = (const float*)d_in[5];
  const float* wd_f  = (const float*)d_in[6];
  const float* swg_f = (const float*)d_in[7];
  const float* swu_f = (const float*)d_in[8];
  const float* swd_f = (const float*)d_in[9];
  const float* sgate = (const float*)d_in[10];
  float* out = (float*)d_out;

  char* ws = (char*)d_ws;
  unsigned short* wgb = (unsigned short*)(ws + OFF_WG);
  unsigned short* wub = (unsigned short*)(ws + OFF_WU);
  unsigned short* wdb = (unsigned short*)(ws + OFF_WD);
  unsigned short* hf  = (unsigned short*)(ws + OFF_HF);
  unsigned short* P   = (unsigned short*)(ws + OFF_P);
  unsigned short* slot = (unsigned short*)(ws + OFF_SLOT);
  int*   top_i   = (int*)(ws + OFF_TOPI);
  float* top_w   = (float*)(ws + OFF_TOPW);
  int*   meta    = (int*)(ws + OFF_META);
  int*   ltok    = (int*)(ws + OFF_LTOK);
  float* lw      = (float*)(ws + OFF_LW);
  int*   rowslot = (int*)(ws + OFF_ROWS);

  hipFuncSetAttribute((const void*)gemm1_kernel,
                      hipFuncAttributeMaxDynamicSharedMemorySize, 131072);
  hipFuncSetAttribute((const void*)gemm2_kernel,
                      hipFuncAttributeMaxDynamicSharedMemorySize, 65536);

  // zero META (count/sum accumulators, cursors) + LTOK + LW (pad-row init:
  // token 0 / weight 0.0f are all-zero bit patterns)
  hipMemsetAsync(ws + OFF_META, 0, 4096ull + (size_t)ROWS_PAD * 8ull, stream);

  // router (blocks 0..1023, with fused aux partial sums) runs concurrently
  // with fp32->bf16 weight cvt (blocks 1024..3071).
  router_cvt_kernel<<<1024 + CVT_BLKS, 256, 0, stream>>>(
      x, lnw, lnb, rw, wg_f, wu_f, wd_f, swg_f, swu_f, swd_f,
      wgb, wub, wdb, hf, top_i, top_w, meta);
  aux_kernel<<<1, 64, 0, stream>>>(meta, out + (size_t)TTOK * HDIM);
  scatter_kernel<<<32, 256, 0, stream>>>(top_i, top_w, meta, ltok, lw, rowslot);

  gemm1_kernel<<<dim3(16, MT_MAX), 512, 131072, stream>>>(hf, wgb, wub, P, meta, ltok);
  gemm2_kernel<<<dim3(8, 2 * MT_MAX), 256, 65536, stream>>>(P, wdb, slot, meta, lw, sgate);
  combine_kernel<<<TTOK * HDIM / 4 / 256, 256, 0, stream>>>(slot, rowslot, meta, out);
}

// Round 11
// 369.136 us; speedup vs baseline: 1.1808x; 1.1808x over previous
//
#include <hip/hip_runtime.h>
#include <hip/hip_bf16.h>
#include <cstdint>
#include <cstddef>

// ---------------- types ----------------
typedef __attribute__((ext_vector_type(8))) short bf16x8;
typedef __attribute__((ext_vector_type(4))) float f32x4;

#define HDIM 1024
#define IDIM 2048
#define TTOK 4096
#define NEXP 8
#define ROWS_PAD 14336          // 256-padded routed (<=10240) + shared 4096
#define MT_MAX 64               // max 256-row m-tiles: <=40 routed + 16 shared
#define EXP_W_ELEMS 2097152ull  // 2048*1024 elems per weight matrix per expert

// ---------------- workspace layout (bytes) ----------------
#define OFF_WG   0ull
#define OFF_WU   (OFF_WG + 9ull * EXP_W_ELEMS * 2ull)
#define OFF_WD   (OFF_WU + 9ull * EXP_W_ELEMS * 2ull)
#define OFF_HF   (OFF_WD + 9ull * EXP_W_ELEMS * 2ull)            // [4096][1024] bf16
#define OFF_P    (OFF_HF + 4096ull * 1024ull * 2ull)             // [ROWS_PAD][2048] bf16
#define OFF_SLOT (OFF_P  + (size_t)ROWS_PAD * 2048ull * 2ull)    // [ROWS_PAD][1024] bf16
#define OFF_TOPI (OFF_SLOT + (size_t)ROWS_PAD * 1024ull * 2ull)  // [8192] int
#define OFF_TOPW (OFF_TOPI + 8192ull * 4ull)                     // [8192] f32
#define OFF_META (OFF_TOPW + 8192ull * 4ull)                     // 4096B ints, see below
#define OFF_LTOK (OFF_META + 4096ull)                            // [ROWS_PAD] int
#define OFF_LW   (OFF_LTOK + (size_t)ROWS_PAD * 4ull)            // [ROWS_PAD] f32
#define OFF_ROWS (OFF_LW + (size_t)ROWS_PAD * 4ull)              // [8192] int
#define OFF_PART (OFF_ROWS + 8192ull * 4ull)                     // [1024][16] f32 partials

// meta (ints): [16..24]=256-padded base, [32..40]=cursor, [48]=ntiles256,
//              [64..127]=tile->expert, [128..191]=tile->row0.
// META (cursors) + LTOK + LW zeroed by hipMemsetAsync. part: no atomics —
// each router block owns part[blockIdx][0..9] (fixes R10's contended-atomic
// serialization: 18K same-cacheline device atomics cost ~85us).

#define VM_WAIT(n) asm volatile("s_waitcnt vmcnt(" #n ")" ::: "memory")
#define SBAR __builtin_amdgcn_s_barrier()
#define FENCE __builtin_amdgcn_sched_barrier(0)
#define PRIO_HI __builtin_amdgcn_s_setprio(1)
#define PRIO_LO __builtin_amdgcn_s_setprio(0)

__device__ __forceinline__ float clamp500(float v) {
  return fminf(fmaxf(v, -500.f), 500.f);
}

__device__ __forceinline__ unsigned short f2bf(float f) {
  unsigned int u = __float_as_uint(f);
  u += 0x7FFFu + ((u >> 16) & 1u);  // RNE; inputs always finite here
  return (unsigned short)(u >> 16);
}

__device__ __forceinline__ float bf2f(unsigned short u) {
  return __uint_as_float((unsigned)u << 16);
}

// async global->LDS, 16B per lane. LDS dest must be wave-uniform base + lane*16.
__device__ __forceinline__ void stage16(const unsigned short* g, unsigned short* l) {
  __builtin_amdgcn_global_load_lds(
      (const __attribute__((address_space(1))) void*)g,
      (__attribute__((address_space(3))) void*)l, 16, 0, 0);
}

__device__ __forceinline__ f32x4 mfma16(bf16x8 a, bf16x8 b, f32x4 c) {
  return __builtin_amdgcn_mfma_f32_16x16x32_bf16(a, b, c, 0, 0, 0);
}

// ---------------- merged router + weight-conversion kernel ----------------
// blocks [0,1024): one wave per token -> LN, logits, softmax, top2; per-block
// aux partials written NON-ATOMICALLY to part[blockIdx][0..9].
// blocks [1024,3072): grid-stride fp32->bf16 convert of all 6 weight tensors.
#define CVT_BLKS 2048
#define E4 (8ull * EXP_W_ELEMS / 4ull)   // float4s per big matrix (8 experts)
#define S4 (EXP_W_ELEMS / 4ull)          // float4s per shared matrix
__global__ __launch_bounds__(256) void router_cvt_kernel(
    const float* __restrict__ x, const float* __restrict__ lnw,
    const float* __restrict__ lnb, const float* __restrict__ rw,
    const float* __restrict__ wg_f, const float* __restrict__ wu_f,
    const float* __restrict__ wd_f, const float* __restrict__ swg_f,
    const float* __restrict__ swu_f, const float* __restrict__ swd_f,
    unsigned short* __restrict__ wgb, unsigned short* __restrict__ wub,
    unsigned short* __restrict__ wdb,
    unsigned short* __restrict__ hf, int* __restrict__ top_i,
    float* __restrict__ top_w, float* __restrict__ part) {
  if (blockIdx.x >= 1024) {
    // ---- cvt role ----
    size_t i = (size_t)(blockIdx.x - 1024) * 256 + threadIdx.x;
    const size_t stride = (size_t)CVT_BLKS * 256;
    const size_t n4 = 3 * (E4 + S4);
    for (; i < n4; i += stride) {
      size_t j = i;
      const float* src;
      unsigned short* dst;
      if (j < E4) { src = wg_f; dst = wgb; }
      else { j -= E4;
        if (j < S4) { src = swg_f; dst = wgb + 8 * EXP_W_ELEMS; }
        else { j -= S4;
          if (j < E4) { src = wu_f; dst = wub; }
          else { j -= E4;
            if (j < S4) { src = swu_f; dst = wub + 8 * EXP_W_ELEMS; }
            else { j -= S4;
              if (j < E4) { src = wd_f; dst = wdb; }
              else { j -= E4; src = swd_f; dst = wdb + 8 * EXP_W_ELEMS; }
            }
          }
        }
      }
      float4 f = ((const float4*)src)[j];
      uint2 pk;
      pk.x = (unsigned)f2bf(f.x) | ((unsigned)f2bf(f.y) << 16);
      pk.y = (unsigned)f2bf(f.z) | ((unsigned)f2bf(f.w) << 16);
      ((uint2*)dst)[j] = pk;
    }
    return;
  }
  // ---- router role ----
  __shared__ float sred[4][10];
  int wv = threadIdx.x >> 6, lane = threadIdx.x & 63;
  int t = blockIdx.x * 4 + wv;
  const float4* xr = (const float4*)(x + (size_t)t * HDIM);
  float4 v[4];
  float s = 0.f;
#pragma unroll
  for (int j = 0; j < 4; ++j) {
    float4 f = xr[j * 64 + lane];
    f.x = clamp500(f.x); f.y = clamp500(f.y);
    f.z = clamp500(f.z); f.w = clamp500(f.w);
    v[j] = f;
    ushort4 hh;
    hh.x = f2bf(f.x); hh.y = f2bf(f.y); hh.z = f2bf(f.z); hh.w = f2bf(f.w);
    ((ushort4*)hf)[(size_t)t * 256 + j * 64 + lane] = hh;
    s += f.x + f.y + f.z + f.w;
  }
#pragma unroll
  for (int m = 32; m; m >>= 1) s += __shfl_xor(s, m);
  float mu = s * (1.f / HDIM);
  float s2 = 0.f;
#pragma unroll
  for (int j = 0; j < 4; ++j) {
    float4 d = v[j];
    d.x -= mu; d.y -= mu; d.z -= mu; d.w -= mu;
    s2 += d.x * d.x + d.y * d.y + d.z * d.z + d.w * d.w;
  }
#pragma unroll
  for (int m = 32; m; m >>= 1) s2 += __shfl_xor(s2, m);
  float rstd = rsqrtf(s2 * (1.f / HDIM) + 1e-5f);
  float acc[8];
#pragma unroll
  for (int e = 0; e < 8; ++e) acc[e] = 0.f;
#pragma unroll
  for (int j = 0; j < 4; ++j) {
    float4 w = ((const float4*)lnw)[j * 64 + lane];
    float4 b = ((const float4*)lnb)[j * 64 + lane];
    float4 hn;
    hn.x = fminf(fmaxf((v[j].x - mu) * rstd * w.x + b.x, -50.f), 50.f);
    hn.y = fminf(fmaxf((v[j].y - mu) * rstd * w.y + b.y, -50.f), 50.f);
    hn.z = fminf(fmaxf((v[j].z - mu) * rstd * w.z + b.z, -50.f), 50.f);
    hn.w = fminf(fmaxf((v[j].w - mu) * rstd * w.w + b.w, -50.f), 50.f);
#pragma unroll
    for (int e = 0; e < 8; ++e) {
      float4 r = ((const float4*)(rw + e * HDIM))[j * 64 + lane];
      acc[e] += hn.x * r.x + hn.y * r.y + hn.z * r.z + hn.w * r.w;
    }
  }
#pragma unroll
  for (int e = 0; e < 8; ++e) {
    float a = acc[e];
#pragma unroll
    for (int m = 32; m; m >>= 1) a += __shfl_xor(a, m);
    acc[e] = a;
  }
  if (lane == 0) {
    float lg[8], mx = -1e30f;
#pragma unroll
    for (int e = 0; e < 8; ++e) {
      float l = fminf(fmaxf(acc[e], -10.f), 10.f);
      lg[e] = l;
      mx = fmaxf(mx, l);
    }
    float se = 0.f;
    float ex[8];
#pragma unroll
    for (int e = 0; e < 8; ++e) { ex[e] = expf(lg[e] - mx); se += ex[e]; }
    float inv = 1.f / se;
    float pr[8];
#pragma unroll
    for (int e = 0; e < 8; ++e) {
      float p = ex[e] * inv;
      pr[e] = fminf(fmaxf(p, 1e-4f), 1.f);
      sred[wv][e] = pr[e];
    }
    int i0 = 0; float v0 = pr[0];
#pragma unroll
    for (int e = 1; e < 8; ++e) if (pr[e] > v0) { v0 = pr[e]; i0 = e; }
    int i1 = -1; float v1 = -1.f;
#pragma unroll
    for (int e = 0; e < 8; ++e) if (e != i0 && pr[e] > v1) { v1 = pr[e]; i1 = e; }
    float dsum = fmaxf(v0 + v1, 1e-4f);
    top_i[2 * t] = i0; top_i[2 * t + 1] = i1;
    top_w[2 * t] = v0 / dsum; top_w[2 * t + 1] = v1 / dsum;
    float lse = mx + logf(se);
    sred[wv][8] = lse * lse;
    float ent = 0.f;
#pragma unroll
    for (int e = 0; e < 8; ++e) {
      float ps = fminf(fmaxf(pr[e], 1e-4f), 1.f - 1e-4f);
      ent -= ps * logf(ps);
    }
    sred[wv][9] = ent;
  }
  __syncthreads();
  if (threadIdx.x < 10) {
    float sm = sred[0][threadIdx.x] + sred[1][threadIdx.x] +
               sred[2][threadIdx.x] + sred[3][threadIdx.x];
    part[blockIdx.x * 16 + threadIdx.x] = sm;   // private slot, no atomics
  }
}

// ---------------- aux loss + 256-padded tile map (one 256-thread block) ----------------
__global__ __launch_bounds__(256) void aux_kernel(
    const int* __restrict__ top_i, const float* __restrict__ part,
    int* __restrict__ meta, float* __restrict__ aux_out) {
  __shared__ int sc[8];
  __shared__ float red[256];
  __shared__ float sums[10];
  int tid = threadIdx.x;
  if (tid < 8) sc[tid] = 0;
  __syncthreads();
  for (int s = tid; s < 8192; s += 256) atomicAdd(&sc[top_i[s]], 1);
  for (int k = 0; k < 10; ++k) {
    float v = 0.f;
    for (int b = tid; b < 1024; b += 256) v += part[b * 16 + k];
    red[tid] = v;
    __syncthreads();
    for (int off = 128; off; off >>= 1) {
      if (tid < off) red[tid] += red[tid + off];
      __syncthreads();
    }
    if (tid == 0) sums[k] = red[0];
    __syncthreads();
  }
  if (tid == 0) {
    float lb = 0.f, usage = 0.f;
    for (int e = 0; e < 8; ++e) {
      float tpe = (float)sc[e] / 8192.f;
      float avg = sums[e] / 4096.f;
      lb += tpe * avg;
      usage += (tpe > 0.01f) ? 1.f : 0.f;
    }
    lb *= 8.f;
    float z_loss = (sums[8] / 4096.f) * 0.001f;
    float ent_loss = fmaxf(logf(8.f) - sums[9] / 4096.f, 0.f) * 0.01f;
    float util = (1.f - usage / 8.f) * 0.1f;
    *aux_out = fminf(fmaxf(lb + z_loss + ent_loss + util, 0.f), 10.f);
    // 256-padded tile map
    int base = 0, tct = 0;
    for (int e = 0; e < 8; ++e) {
      meta[16 + e] = base;
      int nt = (sc[e] + 255) >> 8;
      for (int i = 0; i < nt; ++i) { meta[64 + tct] = e; meta[128 + tct] = base + i * 256; ++tct; }
      base += nt * 256;
    }
    meta[16 + 8] = base;      // shared padded base
    for (int i = 0; i < 16; ++i) { meta[64 + tct] = 8; meta[128 + tct] = base + i * 256; ++tct; }
    meta[48] = tct;
  }
}

// ---------------- scatter tokens into per-expert padded lists ----------------
// (pad entries already zeroed by the launch-time memset: ltok=0, lw=0.0f)
__global__ __launch_bounds__(256) void scatter_kernel(
    const int* __restrict__ top_i, const float* __restrict__ top_w,
    int* __restrict__ meta, int* __restrict__ ltok, float* __restrict__ lw,
    int* __restrict__ rowslot) {
  int s = blockIdx.x * 256 + threadIdx.x;
  if (s < 8192) {
    int e = top_i[s];
    int pos = atomicAdd(&meta[32 + e], 1);
    int idx = meta[16 + e] + pos;
    ltok[idx] = s >> 1;
    lw[idx] = top_w[s];
    rowslot[s] = idx;
  }
  if (s < TTOK) {  // identity list for shared expert
    int sb = meta[16 + 8];
    ltok[sb + s] = s;
    lw[sb + s] = 1.f;
  }
}

// ---------------- GEMM1: P = clamp(silu(clamp(A*Wg^T)) * clamp(A*Wu^T)) ----------------
// BM=256, BN=128 (G and U), BK=64, 8 waves (2x4). All operands bf16 via
// global_load_lds. Pipelined: 8 stages for buf nxt at iter top, vmcnt(8)
// waits only the previous iter's loads, 2 barriers/iter. (Proven R4/R8 structure.)
__global__ __launch_bounds__(512, 1) void gemm1_kernel(
    const unsigned short* __restrict__ hf,
    const unsigned short* __restrict__ wg_all,
    const unsigned short* __restrict__ wu_all,
    unsigned short* __restrict__ P,
    const int* __restrict__ meta, const int* __restrict__ ltok) {
  int mt = blockIdx.y, nt = blockIdx.x;
  if (mt >= meta[48]) return;
  int ex = meta[64 + mt];
  int r0 = meta[128 + mt];
  extern __shared__ unsigned short lds[];
  unsigned short* sA = lds;          // 2 x 16384 elems (256x64)
  unsigned short* sG = lds + 32768;  // 2 x 8192  (128x64)
  unsigned short* sU = lds + 49152;  // 2 x 8192
  int tid = threadIdx.x, lane = tid & 63, wv = tid >> 6;
  int wr = wv >> 2, wc = wv & 3;
  int l15 = lane & 15, l4 = lane >> 4;
  int srow = tid >> 3;              // staging row within a 64-row issue
  int gch = (tid & 7) ^ (srow & 7); // inverse-swizzled source 16B chunk
  int ldst = tid * 8;               // linear LDS dest elems within an issue
  const unsigned short* wg = wg_all + (size_t)ex * EXP_W_ELEMS;
  const unsigned short* wu = wu_all + (size_t)ex * EXP_W_ELEMS;
  int n0 = nt * 128;
  const unsigned short* srcA[4];
#pragma unroll
  for (int i = 0; i < 4; ++i) {
    int tok = ltok[r0 + i * 64 + srow];
    srcA[i] = hf + (size_t)tok * HDIM + gch * 8;
  }
  const unsigned short* srcG[2];
  const unsigned short* srcU[2];
#pragma unroll
  for (int i = 0; i < 2; ++i) {
    srcG[i] = wg + (size_t)(n0 + i * 64 + srow) * HDIM + gch * 8;
    srcU[i] = wu + (size_t)(n0 + i * 64 + srow) * HDIM + gch * 8;
  }
  // swizzled ds_read chunk per kk (row&7 == lane&7 for all frag rows)
  int ch0 = (0 + l4) ^ (lane & 7);
  int ch1 = (4 + l4) ^ (lane & 7);
  int baseA = (wr * 128 + l15) * 64;
  int baseG = (wc * 32 + l15) * 64;

  f32x4 zero = {0.f, 0.f, 0.f, 0.f};
  f32x4 accg[8][2], accu[8][2];
#pragma unroll
  for (int m = 0; m < 8; ++m)
#pragma unroll
    for (int n = 0; n < 2; ++n) { accg[m][n] = zero; accu[m][n] = zero; }

  // prologue: stage K-step 0 into buf0 (no wait here; t=0 top waits)
#pragma unroll
  for (int i = 0; i < 4; ++i) stage16(srcA[i], &sA[i * 4096 + ldst]);
#pragma unroll
  for (int i = 0; i < 2; ++i) stage16(srcG[i], &sG[i * 4096 + ldst]);
#pragma unroll
  for (int i = 0; i < 2; ++i) stage16(srcU[i], &sU[i * 4096 + ldst]);

  for (int t = 0; t < 16; ++t) {
    int cur = t & 1, nxt = cur ^ 1;
    int cbA = cur * 16384, cbG = cur * 8192;
    int nbA = nxt * 16384, nbG = nxt * 8192;
    if (t < 15) {
      int k1 = (t + 1) * 64;
      stage16(srcA[0] + k1, &sA[nbA + 0 * 4096 + ldst]);
      stage16(srcA[1] + k1, &sA[nbA + 1 * 4096 + ldst]);
      stage16(srcA[2] + k1, &sA[nbA + 2 * 4096 + ldst]);
      stage16(srcA[3] + k1, &sA[nbA + 3 * 4096 + ldst]);
      stage16(srcG[0] + k1, &sG[nbG + 0 * 4096 + ldst]);
      stage16(srcG[1] + k1, &sG[nbG + 1 * 4096 + ldst]);
      stage16(srcU[0] + k1, &sU[nbG + 0 * 4096 + ldst]);
      stage16(srcU[1] + k1, &sU[nbG + 1 * 4096 + ldst]);
      VM_WAIT(8);   // previous iter's 8 (buf cur) landed; these 8 stay in flight
    } else {
      VM_WAIT(0);
    }
    SBAR; FENCE;    // all waves' cur stages landed
    bf16x8 af0[8], af1[8], g0[2], g1[2], u0[2], u1[2];
    // ---- kk0 ----
#pragma unroll
    for (int m = 0; m < 8; ++m)
      af0[m] = *(const bf16x8*)&sA[cbA + baseA + m * 1024 + ch0 * 8];
#pragma unroll
    for (int n = 0; n < 2; ++n)
      g0[n] = *(const bf16x8*)&sG[cbG + baseG + n * 1024 + ch0 * 8];
    PRIO_HI;
#pragma unroll
    for (int m = 0; m < 8; ++m)
#pragma unroll
      for (int n = 0; n < 2; ++n)
        accg[m][n] = mfma16(af0[m], g0[n], accg[m][n]);
    PRIO_LO;
#pragma unroll
    for (int n = 0; n < 2; ++n)
      u0[n] = *(const bf16x8*)&sU[cbG + baseG + n * 1024 + ch0 * 8];
    PRIO_HI;
#pragma unroll
    for (int m = 0; m < 8; ++m)
#pragma unroll
      for (int n = 0; n < 2; ++n)
        accu[m][n] = mfma16(af0[m], u0[n], accu[m][n]);
    PRIO_LO;
    // ---- kk1 ----
#pragma unroll
    for (int m = 0; m < 8; ++m)
      af1[m] = *(const bf16x8*)&sA[cbA + baseA + m * 1024 + ch1 * 8];
#pragma unroll
    for (int n = 0; n < 2; ++n)
      g1[n] = *(const bf16x8*)&sG[cbG + baseG + n * 1024 + ch1 * 8];
    PRIO_HI;
#pragma unroll
    for (int m = 0; m < 8; ++m)
#pragma unroll
      for (int n = 0; n < 2; ++n)
        accg[m][n] = mfma16(af1[m], g1[n], accg[m][n]);
    PRIO_LO;
#pragma unroll
    for (int n = 0; n < 2; ++n)
      u1[n] = *(const bf16x8*)&sU[cbG + baseG + n * 1024 + ch1 * 8];
    PRIO_HI;
#pragma unroll
    for (int m = 0; m < 8; ++m)
#pragma unroll
      for (int n = 0; n < 2; ++n)
        accu[m][n] = mfma16(af1[m], u1[n], accu[m][n]);
    PRIO_LO;
    FENCE; SBAR;    // all waves done reading cur before t+1 overwrites it
  }
  // epilogue: SwiGLU, write bf16 P (padded rows junk, never read)
  int rbase = r0 + wr * 128 + l4 * 4;
  int cbase = n0 + wc * 32 + l15;
#pragma unroll
  for (int m = 0; m < 8; ++m) {
#pragma unroll
    for (int r = 0; r < 4; ++r) {
      size_t prow = (size_t)(rbase + m * 16 + r) * IDIM;
#pragma unroll
      for (int n = 0; n < 2; ++n) {
        float g = clamp500(accg[m][n][r]);
        float u = clamp500(accu[m][n][r]);
        float sl = g / (1.f + __expf(-g));
        float p = clamp500(sl * u);
        P[prow + cbase + n * 16] = f2bf(p);
      }
    }
  }
}

// ---------------- GEMM2: slot = weight * clamp(P*Wd^T)  (shared: clamp(clamp(.)*sig)) ----------------
// BM=128, BN=128, BK=64, 4 waves (2x2), 64KB LDS -> 2 blocks/CU. Grid x = 8.
__global__ __launch_bounds__(256) void gemm2_kernel(
    const unsigned short* __restrict__ P,
    const unsigned short* __restrict__ wd_all,
    unsigned short* __restrict__ slot,
    const int* __restrict__ meta, const float* __restrict__ lw,
    const float* __restrict__ sgate) {
  int mt2 = blockIdx.y, nt = blockIdx.x;
  int tile = mt2 >> 1;
  if (tile >= meta[48]) return;
  int ex = meta[64 + tile];
  int r0 = meta[128 + tile] + (mt2 & 1) * 128;
  extern __shared__ unsigned short lds[];
  unsigned short* sA = lds;          // 2 x 8192 (128x64)
  unsigned short* sB = lds + 16384;  // 2 x 8192 (128x64)
  int tid = threadIdx.x, lane = tid & 63, wv = tid >> 6;
  int wr = wv >> 1, wc = wv & 1;
  int l15 = lane & 15, l4 = lane >> 4;
  int srow = tid >> 3;              // staging row within a 32-row issue
  int gch = (tid & 7) ^ (srow & 7);
  int ldst = tid * 8;               // 2048 elems per issue
  const unsigned short* wd = wd_all + (size_t)ex * EXP_W_ELEMS;
  int n0 = nt * 128;
  const unsigned short* srcA[4];
  const unsigned short* srcB[4];
#pragma unroll
  for (int i = 0; i < 4; ++i) {
    srcA[i] = P + (size_t)(r0 + i * 32 + srow) * IDIM + gch * 8;
    srcB[i] = wd + (size_t)(n0 + i * 32 + srow) * IDIM + gch * 8;
  }
  int ch0 = (0 + l4) ^ (lane & 7);
  int ch1 = (4 + l4) ^ (lane & 7);
  int baseA = (wr * 64 + l15) * 64;
  int baseB = (wc * 64 + l15) * 64;

  f32x4 zero = {0.f, 0.f, 0.f, 0.f};
  f32x4 acc[4][4];
#pragma unroll
  for (int m = 0; m < 4; ++m)
#pragma unroll
    for (int n = 0; n < 4; ++n) acc[m][n] = zero;

  // prologue
#pragma unroll
  for (int i = 0; i < 4; ++i) stage16(srcA[i], &sA[i * 2048 + ldst]);
#pragma unroll
  for (int i = 0; i < 4; ++i) stage16(srcB[i], &sB[i * 2048 + ldst]);

  for (int t = 0; t < 32; ++t) {
    int cur = t & 1, nxt = cur ^ 1;
    int cb = cur * 8192, nb = nxt * 8192;
    if (t < 31) {
      int k1 = (t + 1) * 64;
      stage16(srcA[0] + k1, &sA[nb + 0 * 2048 + ldst]);
      stage16(srcA[1] + k1, &sA[nb + 1 * 2048 + ldst]);
      stage16(srcA[2] + k1, &sA[nb + 2 * 2048 + ldst]);
      stage16(srcA[3] + k1, &sA[nb + 3 * 2048 + ldst]);
      stage16(srcB[0] + k1, &sB[nb + 0 * 2048 + ldst]);
      stage16(srcB[1] + k1, &sB[nb + 1 * 2048 + ldst]);
      stage16(srcB[2] + k1, &sB[nb + 2 * 2048 + ldst]);
      stage16(srcB[3] + k1, &sB[nb + 3 * 2048 + ldst]);
      VM_WAIT(8);
    } else {
      VM_WAIT(0);
    }
    SBAR; FENCE;
    bf16x8 af0[4], af1[4], b0[4], b1[4];
    // ---- kk0 ----
#pragma unroll
    for (int m = 0; m < 4; ++m)
      af0[m] = *(const bf16x8*)&sA[cb + baseA + m * 1024 + ch0 * 8];
#pragma unroll
    for (int n = 0; n < 4; ++n)
      b0[n] = *(const bf16x8*)&sB[cb + baseB + n * 1024 + ch0 * 8];
    PRIO_HI;
#pragma unroll
    for (int m = 0; m < 4; ++m)
#pragma unroll
      for (int n = 0; n < 4; ++n)
        acc[m][n] = mfma16(af0[m], b0[n], acc[m][n]);
    PRIO_LO;
    // ---- kk1 ----
#pragma unroll
    for (int m = 0; m < 4; ++m)
      af1[m] = *(const bf16x8*)&sA[cb + baseA + m * 1024 + ch1 * 8];
#pragma unroll
    for (int n = 0; n < 4; ++n)
      b1[n] = *(const bf16x8*)&sB[cb + baseB + n * 1024 + ch1 * 8];
    PRIO_HI;
#pragma unroll
    for (int m = 0; m < 4; ++m)
#pragma unroll
      for (int n = 0; n < 4; ++n)
        acc[m][n] = mfma16(af1[m], b1[n], acc[m][n]);
    PRIO_LO;
    FENCE; SBAR;
  }
  float gsig = 1.f / (1.f + __expf(-sgate[0]));
  int rbase = r0 + wr * 64 + l4 * 4;
  int cbase = n0 + wc * 64 + l15;
#pragma unroll
  for (int m = 0; m < 4; ++m) {
#pragma unroll
    for (int r = 0; r < 4; ++r) {
      int row = rbase + m * 16 + r;
      float wgt = (ex == 8) ? 1.f : lw[row];
      size_t srow_o = (size_t)row * HDIM;
#pragma unroll
      for (int n = 0; n < 4; ++n) {
        float o = clamp500(acc[m][n][r]);
        float val = (ex == 8) ? clamp500(o * gsig) : wgt * o;
        slot[srow_o + cbase + n * 16] = f2bf(val);
      }
    }
  }
}

// ---------------- combine: final = clamp(slot0 + slot1 + shared) ----------------
__global__ __launch_bounds__(256) void combine_kernel(
    const unsigned short* __restrict__ slot, const int* __restrict__ rowslot,
    const int* __restrict__ meta, float* __restrict__ out) {
  int i = blockIdx.x * 256 + threadIdx.x;  // 4-elem group index
  int t = i >> 8;
  int c = (i & 255) * 4;
  int sb = meta[16 + 8];
  int r0 = rowslot[2 * t], r1 = rowslot[2 * t + 1];
  ushort4 va = *(const ushort4*)(slot + (size_t)r0 * HDIM + c);
  ushort4 vb = *(const ushort4*)(slot + (size_t)r1 * HDIM + c);
  ushort4 vs = *(const ushort4*)(slot + (size_t)(sb + t) * HDIM + c);
  float4 o;
  o.x = clamp500(bf2f(va.x) + bf2f(vb.x) + bf2f(vs.x));
  o.y = clamp500(bf2f(va.y) + bf2f(vb.y) + bf2f(vs.y));
  o.z = clamp500(bf2f(va.z) + bf2f(vb.z) + bf2f(vs.z));
  o.w = clamp500(bf2f(va.w) + bf2f(vb.w) + bf2f(vs.w));
  *(float4*)(out + (size_t)t * HDIM + c) = o;
}

// ---------------- launch ----------------
extern "C" void kernel_launch(void* const* d_in, const int* in_sizes, int n_in,
                              void* d_out, int out_size, void* d_ws, size_t ws_size,
                              hipStream_t stream) {
  const float* x     = (const float*)d_in[0];
  const float* lnw   = (const float*)d_in[1];
  const float* lnb   = (const float*)d_in[2];
  const float* rw    = (const float*)d_in[3];
  const float* wg_f  = (const float*)d_in[4];
  const float* wu_f  = (const float*)d_in[5];
  const float* wd_f  = (const float*)d_in[6];
  const float* swg_f = (const float*)d_in[7];
  const float* swu_f = (const float*)d_in[8];
  const float* swd_f = (const float*)d_in[9];
  const float* sgate = (const float*)d_in[10];
  float* out = (float*)d_out;

  char* ws = (char*)d_ws;
  unsigned short* wgb = (unsigned short*)(ws + OFF_WG);
  unsigned short* wub = (unsigned short*)(ws + OFF_WU);
  unsigned short* wdb = (unsigned short*)(ws + OFF_WD);
  unsigned short* hf  = (unsigned short*)(ws + OFF_HF);
  unsigned short* P   = (unsigned short*)(ws + OFF_P);
  unsigned short* slot = (unsigned short*)(ws + OFF_SLOT);
  int*   top_i   = (int*)(ws + OFF_TOPI);
  float* top_w   = (float*)(ws + OFF_TOPW);
  int*   meta    = (int*)(ws + OFF_META);
  int*   ltok    = (int*)(ws + OFF_LTOK);
  float* lw      = (float*)(ws + OFF_LW);
  int*   rowslot = (int*)(ws + OFF_ROWS);
  float* part    = (float*)(ws + OFF_PART);

  hipFuncSetAttribute((const void*)gemm1_kernel,
                      hipFuncAttributeMaxDynamicSharedMemorySize, 131072);
  hipFuncSetAttribute((const void*)gemm2_kernel,
                      hipFuncAttributeMaxDynamicSharedMemorySize, 65536);

  // zero META (cursors) + LTOK + LW (pad-row init: token 0 / weight 0.0f)
  hipMemsetAsync(ws + OFF_META, 0, 4096ull + (size_t)ROWS_PAD * 8ull, stream);

  // router (blocks 0..1023, non-atomic per-block aux partials) runs
  // concurrently with fp32->bf16 weight cvt (blocks 1024..3071).
  router_cvt_kernel<<<1024 + CVT_BLKS, 256, 0, stream>>>(
      x, lnw, lnb, rw, wg_f, wu_f, wd_f, swg_f, swu_f, swd_f,
      wgb, wub, wdb, hf, top_i, top_w, part);
  aux_kernel<<<1, 256, 0, stream>>>(top_i, part, meta, out + (size_t)TTOK * HDIM);
  scatter_kernel<<<32, 256, 0, stream>>>(top_i, top_w, meta, ltok, lw, rowslot);

  gemm1_kernel<<<dim3(16, MT_MAX), 512, 131072, stream>>>(hf, wgb, wub, P, meta, ltok);
  gemm2_kernel<<<dim3(8, 2 * MT_MAX), 256, 65536, stream>>>(P, wdb, slot, meta, lw, sgate);
  combine_kernel<<<TTOK * HDIM / 4 / 256, 256, 0, stream>>>(slot, rowslot, meta, out);
}

// Round 12
// 338.659 us; speedup vs baseline: 1.2871x; 1.0900x over previous
//
#include <hip/hip_runtime.h>
#include <hip/hip_bf16.h>
#include <cstdint>
#include <cstddef>

// ---------------- types ----------------
typedef __attribute__((ext_vector_type(8))) short bf16x8;
typedef __attribute__((ext_vector_type(4))) float f32x4;

#define HDIM 1024
#define IDIM 2048
#define TTOK 4096
#define NEXP 8
#define ROWS_PAD 14336          // 256-padded routed (<=10240) + shared 4096
#define MT_MAX 64               // max 256-row m-tiles: <=40 routed + 16 shared
#define EXP_W_ELEMS 2097152ull  // 2048*1024 elems per weight matrix per expert

// ---------------- workspace layout (bytes) ----------------
#define OFF_WG   0ull
#define OFF_WU   (OFF_WG + 9ull * EXP_W_ELEMS * 2ull)
#define OFF_WD   (OFF_WU + 9ull * EXP_W_ELEMS * 2ull)
#define OFF_HF   (OFF_WD + 9ull * EXP_W_ELEMS * 2ull)            // [4096][1024] bf16
#define OFF_P    (OFF_HF + 4096ull * 1024ull * 2ull)             // [ROWS_PAD][2048] bf16
#define OFF_SLOT (OFF_P  + (size_t)ROWS_PAD * 2048ull * 2ull)    // [ROWS_PAD][1024] bf16
#define OFF_TOPI (OFF_SLOT + (size_t)ROWS_PAD * 1024ull * 2ull)  // [8192] int
#define OFF_TOPW (OFF_TOPI + 8192ull * 4ull)                     // [8192] f32
#define OFF_META (OFF_TOPW + 8192ull * 4ull)                     // 4096B ints, see below
#define OFF_LTOK (OFF_META + 4096ull)                            // [ROWS_PAD] int
#define OFF_LW   (OFF_LTOK + (size_t)ROWS_PAD * 4ull)            // [ROWS_PAD] f32
#define OFF_ROWS (OFF_LW + (size_t)ROWS_PAD * 4ull)              // [8192] int
#define OFF_PART (OFF_ROWS + 8192ull * 4ull)                     // [1024][16] f32 partials

// meta (ints): [16..24]=256-padded base, [32..40]=cursor, [48]=ntiles256,
//              [64..127]=tile->expert, [128..191]=tile->row0.
// META (cursors) + LTOK + LW zeroed by hipMemsetAsync. part: no atomics —
// each router block owns part[blockIdx][0..9] (R10 lesson: ~18K same-line
// device atomics serialized ~85us).

#define VM_WAIT(n) asm volatile("s_waitcnt vmcnt(" #n ")" ::: "memory")
#define SBAR __builtin_amdgcn_s_barrier()
#define FENCE __builtin_amdgcn_sched_barrier(0)
#define PRIO_HI __builtin_amdgcn_s_setprio(1)
#define PRIO_LO __builtin_amdgcn_s_setprio(0)

__device__ __forceinline__ float clamp500(float v) {
  return fminf(fmaxf(v, -500.f), 500.f);
}

__device__ __forceinline__ unsigned short f2bf(float f) {
  unsigned int u = __float_as_uint(f);
  u += 0x7FFFu + ((u >> 16) & 1u);  // RNE; inputs always finite here
  return (unsigned short)(u >> 16);
}

__device__ __forceinline__ float bf2f(unsigned short u) {
  return __uint_as_float((unsigned)u << 16);
}

// async global->LDS, 16B per lane. LDS dest must be wave-uniform base + lane*16.
__device__ __forceinline__ void stage16(const unsigned short* g, unsigned short* l) {
  __builtin_amdgcn_global_load_lds(
      (const __attribute__((address_space(1))) void*)g,
      (__attribute__((address_space(3))) void*)l, 16, 0, 0);
}

__device__ __forceinline__ f32x4 mfma16(bf16x8 a, bf16x8 b, f32x4 c) {
  return __builtin_amdgcn_mfma_f32_16x16x32_bf16(a, b, c, 0, 0, 0);
}

__device__ __forceinline__ void cvt4(const float* __restrict__ src,
                                     unsigned short* __restrict__ dst, size_t j) {
  float4 f = ((const float4*)src)[j];
  uint2 pk;
  pk.x = (unsigned)f2bf(f.x) | ((unsigned)f2bf(f.y) << 16);
  pk.y = (unsigned)f2bf(f.z) | ((unsigned)f2bf(f.w) << 16);
  ((uint2*)dst)[j] = pk;
}

// ---------------- merged router + wg/wu weight-conversion kernel ----------------
// blocks [0,1024): one wave per token -> LN, logits, softmax, top2; per-block
// aux partials written NON-ATOMICALLY to part[blockIdx][0..9].
// blocks [1024,3072): grid-stride fp32->bf16 convert of wg,wu (+shared g,u).
// wd conversion rides inside gemm1's grid (only gemm2 needs it).
#define CVT_BLKS 2048
#define E4 (8ull * EXP_W_ELEMS / 4ull)   // float4s per big matrix (8 experts)
#define S4 (EXP_W_ELEMS / 4ull)          // float4s per shared matrix
__global__ __launch_bounds__(256) void router_cvt_kernel(
    const float* __restrict__ x, const float* __restrict__ lnw,
    const float* __restrict__ lnb, const float* __restrict__ rw,
    const float* __restrict__ wg_f, const float* __restrict__ wu_f,
    const float* __restrict__ swg_f, const float* __restrict__ swu_f,
    unsigned short* __restrict__ wgb, unsigned short* __restrict__ wub,
    unsigned short* __restrict__ hf, int* __restrict__ top_i,
    float* __restrict__ top_w, float* __restrict__ part) {
  if (blockIdx.x >= 1024) {
    // ---- cvt role: wg, swg, wu, swu ----
    size_t i = (size_t)(blockIdx.x - 1024) * 256 + threadIdx.x;
    const size_t stride = (size_t)CVT_BLKS * 256;
    const size_t n4 = 2 * (E4 + S4);
    for (; i < n4; i += stride) {
      size_t j = i;
      if (j < E4) { cvt4(wg_f, wgb, j); }
      else { j -= E4;
        if (j < S4) { cvt4(swg_f, wgb + 8 * EXP_W_ELEMS, j); }
        else { j -= S4;
          if (j < E4) { cvt4(wu_f, wub, j); }
          else { j -= E4; cvt4(swu_f, wub + 8 * EXP_W_ELEMS, j); }
        }
      }
    }
    return;
  }
  // ---- router role ----
  __shared__ float sred[4][10];
  int wv = threadIdx.x >> 6, lane = threadIdx.x & 63;
  int t = blockIdx.x * 4 + wv;
  const float4* xr = (const float4*)(x + (size_t)t * HDIM);
  float4 v[4];
  float s = 0.f;
#pragma unroll
  for (int j = 0; j < 4; ++j) {
    float4 f = xr[j * 64 + lane];
    f.x = clamp500(f.x); f.y = clamp500(f.y);
    f.z = clamp500(f.z); f.w = clamp500(f.w);
    v[j] = f;
    ushort4 hh;
    hh.x = f2bf(f.x); hh.y = f2bf(f.y); hh.z = f2bf(f.z); hh.w = f2bf(f.w);
    ((ushort4*)hf)[(size_t)t * 256 + j * 64 + lane] = hh;
    s += f.x + f.y + f.z + f.w;
  }
#pragma unroll
  for (int m = 32; m; m >>= 1) s += __shfl_xor(s, m);
  float mu = s * (1.f / HDIM);
  float s2 = 0.f;
#pragma unroll
  for (int j = 0; j < 4; ++j) {
    float4 d = v[j];
    d.x -= mu; d.y -= mu; d.z -= mu; d.w -= mu;
    s2 += d.x * d.x + d.y * d.y + d.z * d.z + d.w * d.w;
  }
#pragma unroll
  for (int m = 32; m; m >>= 1) s2 += __shfl_xor(s2, m);
  float rstd = rsqrtf(s2 * (1.f / HDIM) + 1e-5f);
  float acc[8];
#pragma unroll
  for (int e = 0; e < 8; ++e) acc[e] = 0.f;
#pragma unroll
  for (int j = 0; j < 4; ++j) {
    float4 w = ((const float4*)lnw)[j * 64 + lane];
    float4 b = ((const float4*)lnb)[j * 64 + lane];
    float4 hn;
    hn.x = fminf(fmaxf((v[j].x - mu) * rstd * w.x + b.x, -50.f), 50.f);
    hn.y = fminf(fmaxf((v[j].y - mu) * rstd * w.y + b.y, -50.f), 50.f);
    hn.z = fminf(fmaxf((v[j].z - mu) * rstd * w.z + b.z, -50.f), 50.f);
    hn.w = fminf(fmaxf((v[j].w - mu) * rstd * w.w + b.w, -50.f), 50.f);
#pragma unroll
    for (int e = 0; e < 8; ++e) {
      float4 r = ((const float4*)(rw + e * HDIM))[j * 64 + lane];
      acc[e] += hn.x * r.x + hn.y * r.y + hn.z * r.z + hn.w * r.w;
    }
  }
#pragma unroll
  for (int e = 0; e < 8; ++e) {
    float a = acc[e];
#pragma unroll
    for (int m = 32; m; m >>= 1) a += __shfl_xor(a, m);
    acc[e] = a;
  }
  if (lane == 0) {
    float lg[8], mx = -1e30f;
#pragma unroll
    for (int e = 0; e < 8; ++e) {
      float l = fminf(fmaxf(acc[e], -10.f), 10.f);
      lg[e] = l;
      mx = fmaxf(mx, l);
    }
    float se = 0.f;
    float ex[8];
#pragma unroll
    for (int e = 0; e < 8; ++e) { ex[e] = expf(lg[e] - mx); se += ex[e]; }
    float inv = 1.f / se;
    float pr[8];
#pragma unroll
    for (int e = 0; e < 8; ++e) {
      float p = ex[e] * inv;
      pr[e] = fminf(fmaxf(p, 1e-4f), 1.f);
      sred[wv][e] = pr[e];
    }
    int i0 = 0; float v0 = pr[0];
#pragma unroll
    for (int e = 1; e < 8; ++e) if (pr[e] > v0) { v0 = pr[e]; i0 = e; }
    int i1 = -1; float v1 = -1.f;
#pragma unroll
    for (int e = 0; e < 8; ++e) if (e != i0 && pr[e] > v1) { v1 = pr[e]; i1 = e; }
    float dsum = fmaxf(v0 + v1, 1e-4f);
    top_i[2 * t] = i0; top_i[2 * t + 1] = i1;
    top_w[2 * t] = v0 / dsum; top_w[2 * t + 1] = v1 / dsum;
    float lse = mx + logf(se);
    sred[wv][8] = lse * lse;
    float ent = 0.f;
#pragma unroll
    for (int e = 0; e < 8; ++e) {
      float ps = fminf(fmaxf(pr[e], 1e-4f), 1.f - 1e-4f);
      ent -= ps * logf(ps);
    }
    sred[wv][9] = ent;
  }
  __syncthreads();
  if (threadIdx.x < 10) {
    float sm = sred[0][threadIdx.x] + sred[1][threadIdx.x] +
               sred[2][threadIdx.x] + sred[3][threadIdx.x];
    part[blockIdx.x * 16 + threadIdx.x] = sm;   // private slot, no atomics
  }
}

// ---------------- aux loss + 256-padded tile map (one 256-thread block) ----------------
__global__ __launch_bounds__(256) void aux_kernel(
    const int* __restrict__ top_i, const float* __restrict__ part,
    int* __restrict__ meta, float* __restrict__ aux_out) {
  __shared__ int sc[8];
  __shared__ float red[256];
  __shared__ float sums[10];
  int tid = threadIdx.x;
  if (tid < 8) sc[tid] = 0;
  __syncthreads();
  for (int s = tid; s < 8192; s += 256) atomicAdd(&sc[top_i[s]], 1);
  for (int k = 0; k < 10; ++k) {
    float v = 0.f;
    for (int b = tid; b < 1024; b += 256) v += part[b * 16 + k];
    red[tid] = v;
    __syncthreads();
    for (int off = 128; off; off >>= 1) {
      if (tid < off) red[tid] += red[tid + off];
      __syncthreads();
    }
    if (tid == 0) sums[k] = red[0];
    __syncthreads();
  }
  if (tid == 0) {
    float lb = 0.f, usage = 0.f;
    for (int e = 0; e < 8; ++e) {
      float tpe = (float)sc[e] / 8192.f;
      float avg = sums[e] / 4096.f;
      lb += tpe * avg;
      usage += (tpe > 0.01f) ? 1.f : 0.f;
    }
    lb *= 8.f;
    float z_loss = (sums[8] / 4096.f) * 0.001f;
    float ent_loss = fmaxf(logf(8.f) - sums[9] / 4096.f, 0.f) * 0.01f;
    float util = (1.f - usage / 8.f) * 0.1f;
    *aux_out = fminf(fmaxf(lb + z_loss + ent_loss + util, 0.f), 10.f);
    // 256-padded tile map
    int base = 0, tct = 0;
    for (int e = 0; e < 8; ++e) {
      meta[16 + e] = base;
      int nt = (sc[e] + 255) >> 8;
      for (int i = 0; i < nt; ++i) { meta[64 + tct] = e; meta[128 + tct] = base + i * 256; ++tct; }
      base += nt * 256;
    }
    meta[16 + 8] = base;      // shared padded base
    for (int i = 0; i < 16; ++i) { meta[64 + tct] = 8; meta[128 + tct] = base + i * 256; ++tct; }
    meta[48] = tct;
  }
}

// ---------------- scatter tokens into per-expert padded lists ----------------
// (pad entries already zeroed by the launch-time memset: ltok=0, lw=0.0f)
__global__ __launch_bounds__(256) void scatter_kernel(
    const int* __restrict__ top_i, const float* __restrict__ top_w,
    int* __restrict__ meta, int* __restrict__ ltok, float* __restrict__ lw,
    int* __restrict__ rowslot) {
  int s = blockIdx.x * 256 + threadIdx.x;
  if (s < 8192) {
    int e = top_i[s];
    int pos = atomicAdd(&meta[32 + e], 1);
    int idx = meta[16 + e] + pos;
    ltok[idx] = s >> 1;
    lw[idx] = top_w[s];
    rowslot[s] = idx;
  }
  if (s < TTOK) {  // identity list for shared expert
    int sb = meta[16 + 8];
    ltok[sb + s] = s;
    lw[sb + s] = 1.f;
  }
}

// ---------------- GEMM1: P = clamp(silu(clamp(A*Wg^T)) * clamp(A*Wu^T)) ----------------
// BM=256, BN=128 (G and U), BK=64, 8 waves (2x4), bf16 via global_load_lds,
// vmcnt(8) pipeline (proven R4/R8 structure). Blocks with blockIdx.y >= MT_MAX
// take a wd fp32->bf16 cvt role instead (dispatched last -> overlaps gemm1's
// tail; gemm1 never reads wdb, gemm2 launches after, so no race).
#define WDCVT_YBLKS 16   // 16 x 16 = 256 cvt blocks x 512 thr
__global__ __launch_bounds__(512, 1) void gemm1_kernel(
    const unsigned short* __restrict__ hf,
    const unsigned short* __restrict__ wg_all,
    const unsigned short* __restrict__ wu_all,
    const float* __restrict__ wd_f, const float* __restrict__ swd_f,
    unsigned short* __restrict__ wdb,
    unsigned short* __restrict__ P,
    const int* __restrict__ meta, const int* __restrict__ ltok) {
  int mt = blockIdx.y, nt = blockIdx.x;
  if (mt >= MT_MAX) {
    // ---- wd cvt role ----
    size_t i = ((size_t)(mt - MT_MAX) * 16 + nt) * 512 + threadIdx.x;
    const size_t stride = (size_t)WDCVT_YBLKS * 16 * 512;
    const size_t n4 = E4 + S4;
    for (; i < n4; i += stride) {
      if (i < E4) cvt4(wd_f, wdb, i);
      else cvt4(swd_f, wdb + 8 * EXP_W_ELEMS, i - E4);
    }
    return;
  }
  if (mt >= meta[48]) return;
  int ex = meta[64 + mt];
  int r0 = meta[128 + mt];
  extern __shared__ unsigned short lds[];
  unsigned short* sA = lds;          // 2 x 16384 elems (256x64)
  unsigned short* sG = lds + 32768;  // 2 x 8192  (128x64)
  unsigned short* sU = lds + 49152;  // 2 x 8192
  int tid = threadIdx.x, lane = tid & 63, wv = tid >> 6;
  int wr = wv >> 2, wc = wv & 3;
  int l15 = lane & 15, l4 = lane >> 4;
  int srow = tid >> 3;              // staging row within a 64-row issue
  int gch = (tid & 7) ^ (srow & 7); // inverse-swizzled source 16B chunk
  int ldst = tid * 8;               // linear LDS dest elems within an issue
  const unsigned short* wg = wg_all + (size_t)ex * EXP_W_ELEMS;
  const unsigned short* wu = wu_all + (size_t)ex * EXP_W_ELEMS;
  int n0 = nt * 128;
  const unsigned short* srcA[4];
#pragma unroll
  for (int i = 0; i < 4; ++i) {
    int tok = ltok[r0 + i * 64 + srow];
    srcA[i] = hf + (size_t)tok * HDIM + gch * 8;
  }
  const unsigned short* srcG[2];
  const unsigned short* srcU[2];
#pragma unroll
  for (int i = 0; i < 2; ++i) {
    srcG[i] = wg + (size_t)(n0 + i * 64 + srow) * HDIM + gch * 8;
    srcU[i] = wu + (size_t)(n0 + i * 64 + srow) * HDIM + gch * 8;
  }
  // swizzled ds_read chunk per kk (row&7 == lane&7 for all frag rows)
  int ch0 = (0 + l4) ^ (lane & 7);
  int ch1 = (4 + l4) ^ (lane & 7);
  int baseA = (wr * 128 + l15) * 64;
  int baseG = (wc * 32 + l15) * 64;

  f32x4 zero = {0.f, 0.f, 0.f, 0.f};
  f32x4 accg[8][2], accu[8][2];
#pragma unroll
  for (int m = 0; m < 8; ++m)
#pragma unroll
    for (int n = 0; n < 2; ++n) { accg[m][n] = zero; accu[m][n] = zero; }

  // prologue: stage K-step 0 into buf0 (no wait here; t=0 top waits)
#pragma unroll
  for (int i = 0; i < 4; ++i) stage16(srcA[i], &sA[i * 4096 + ldst]);
#pragma unroll
  for (int i = 0; i < 2; ++i) stage16(srcG[i], &sG[i * 4096 + ldst]);
#pragma unroll
  for (int i = 0; i < 2; ++i) stage16(srcU[i], &sU[i * 4096 + ldst]);

  for (int t = 0; t < 16; ++t) {
    int cur = t & 1, nxt = cur ^ 1;
    int cbA = cur * 16384, cbG = cur * 8192;
    int nbA = nxt * 16384, nbG = nxt * 8192;
    if (t < 15) {
      int k1 = (t + 1) * 64;
      stage16(srcA[0] + k1, &sA[nbA + 0 * 4096 + ldst]);
      stage16(srcA[1] + k1, &sA[nbA + 1 * 4096 + ldst]);
      stage16(srcA[2] + k1, &sA[nbA + 2 * 4096 + ldst]);
      stage16(srcA[3] + k1, &sA[nbA + 3 * 4096 + ldst]);
      stage16(srcG[0] + k1, &sG[nbG + 0 * 4096 + ldst]);
      stage16(srcG[1] + k1, &sG[nbG + 1 * 4096 + ldst]);
      stage16(srcU[0] + k1, &sU[nbG + 0 * 4096 + ldst]);
      stage16(srcU[1] + k1, &sU[nbG + 1 * 4096 + ldst]);
      VM_WAIT(8);   // previous iter's 8 (buf cur) landed; these 8 stay in flight
    } else {
      VM_WAIT(0);
    }
    SBAR; FENCE;    // all waves' cur stages landed
    bf16x8 af0[8], af1[8], g0[2], g1[2], u0[2], u1[2];
    // ---- kk0 ----
#pragma unroll
    for (int m = 0; m < 8; ++m)
      af0[m] = *(const bf16x8*)&sA[cbA + baseA + m * 1024 + ch0 * 8];
#pragma unroll
    for (int n = 0; n < 2; ++n)
      g0[n] = *(const bf16x8*)&sG[cbG + baseG + n * 1024 + ch0 * 8];
    PRIO_HI;
#pragma unroll
    for (int m = 0; m < 8; ++m)
#pragma unroll
      for (int n = 0; n < 2; ++n)
        accg[m][n] = mfma16(af0[m], g0[n], accg[m][n]);
    PRIO_LO;
#pragma unroll
    for (int n = 0; n < 2; ++n)
      u0[n] = *(const bf16x8*)&sU[cbG + baseG + n * 1024 + ch0 * 8];
    PRIO_HI;
#pragma unroll
    for (int m = 0; m < 8; ++m)
#pragma unroll
      for (int n = 0; n < 2; ++n)
        accu[m][n] = mfma16(af0[m], u0[n], accu[m][n]);
    PRIO_LO;
    // ---- kk1 ----
#pragma unroll
    for (int m = 0; m < 8; ++m)
      af1[m] = *(const bf16x8*)&sA[cbA + baseA + m * 1024 + ch1 * 8];
#pragma unroll
    for (int n = 0; n < 2; ++n)
      g1[n] = *(const bf16x8*)&sG[cbG + baseG + n * 1024 + ch1 * 8];
    PRIO_HI;
#pragma unroll
    for (int m = 0; m < 8; ++m)
#pragma unroll
      for (int n = 0; n < 2; ++n)
        accg[m][n] = mfma16(af1[m], g1[n], accg[m][n]);
    PRIO_LO;
#pragma unroll
    for (int n = 0; n < 2; ++n)
      u1[n] = *(const bf16x8*)&sU[cbG + baseG + n * 1024 + ch1 * 8];
    PRIO_HI;
#pragma unroll
    for (int m = 0; m < 8; ++m)
#pragma unroll
      for (int n = 0; n < 2; ++n)
        accu[m][n] = mfma16(af1[m], u1[n], accu[m][n]);
    PRIO_LO;
    FENCE; SBAR;    // all waves done reading cur before t+1 overwrites it
  }
  // epilogue: SwiGLU, write bf16 P (padded rows junk, never read)
  int rbase = r0 + wr * 128 + l4 * 4;
  int cbase = n0 + wc * 32 + l15;
#pragma unroll
  for (int m = 0; m < 8; ++m) {
#pragma unroll
    for (int r = 0; r < 4; ++r) {
      size_t prow = (size_t)(rbase + m * 16 + r) * IDIM;
#pragma unroll
      for (int n = 0; n < 2; ++n) {
        float g = clamp500(accg[m][n][r]);
        float u = clamp500(accu[m][n][r]);
        float sl = g / (1.f + __expf(-g));
        float p = clamp500(sl * u);
        P[prow + cbase + n * 16] = f2bf(p);
      }
    }
  }
}

// ---------------- GEMM2: slot = weight * clamp(P*Wd^T)  (shared: clamp(clamp(.)*sig)) ----------------
// BM=256, BN=256, BK=64, 8 waves (2x4), vmcnt(8) pipeline (proven R8 structure).
__global__ __launch_bounds__(512, 1) void gemm2_kernel(
    const unsigned short* __restrict__ P,
    const unsigned short* __restrict__ wd_all,
    unsigned short* __restrict__ slot,
    const int* __restrict__ meta, const float* __restrict__ lw,
    const float* __restrict__ sgate) {
  int mt = blockIdx.y, nt = blockIdx.x;
  if (mt >= meta[48]) return;
  int ex = meta[64 + mt];
  int r0 = meta[128 + mt];
  extern __shared__ unsigned short lds[];
  unsigned short* sA = lds;          // 2 x 16384 (256x64)
  unsigned short* sB = lds + 32768;  // 2 x 16384 (256x64)
  int tid = threadIdx.x, lane = tid & 63, wv = tid >> 6;
  int wr = wv >> 2, wc = wv & 3;
  int l15 = lane & 15, l4 = lane >> 4;
  int srow = tid >> 3;
  int gch = (tid & 7) ^ (srow & 7);
  int ldst = tid * 8;
  const unsigned short* wd = wd_all + (size_t)ex * EXP_W_ELEMS;
  int n0 = nt * 256;
  const unsigned short* srcA[4];
  const unsigned short* srcB[4];
#pragma unroll
  for (int i = 0; i < 4; ++i) {
    srcA[i] = P + (size_t)(r0 + i * 64 + srow) * IDIM + gch * 8;
    srcB[i] = wd + (size_t)(n0 + i * 64 + srow) * IDIM + gch * 8;
  }
  int ch0 = (0 + l4) ^ (lane & 7);
  int ch1 = (4 + l4) ^ (lane & 7);
  int baseA = (wr * 128 + l15) * 64;
  int baseB = (wc * 64 + l15) * 64;

  f32x4 zero = {0.f, 0.f, 0.f, 0.f};
  f32x4 acc[8][4];
#pragma unroll
  for (int m = 0; m < 8; ++m)
#pragma unroll
    for (int n = 0; n < 4; ++n) acc[m][n] = zero;

  // prologue
#pragma unroll
  for (int i = 0; i < 4; ++i) stage16(srcA[i], &sA[i * 4096 + ldst]);
#pragma unroll
  for (int i = 0; i < 4; ++i) stage16(srcB[i], &sB[i * 4096 + ldst]);

  for (int t = 0; t < 32; ++t) {
    int cur = t & 1, nxt = cur ^ 1;
    int cb = cur * 16384, nb = nxt * 16384;
    if (t < 31) {
      int k1 = (t + 1) * 64;
      stage16(srcA[0] + k1, &sA[nb + 0 * 4096 + ldst]);
      stage16(srcA[1] + k1, &sA[nb + 1 * 4096 + ldst]);
      stage16(srcA[2] + k1, &sA[nb + 2 * 4096 + ldst]);
      stage16(srcA[3] + k1, &sA[nb + 3 * 4096 + ldst]);
      stage16(srcB[0] + k1, &sB[nb + 0 * 4096 + ldst]);
      stage16(srcB[1] + k1, &sB[nb + 1 * 4096 + ldst]);
      stage16(srcB[2] + k1, &sB[nb + 2 * 4096 + ldst]);
      stage16(srcB[3] + k1, &sB[nb + 3 * 4096 + ldst]);
      VM_WAIT(8);
    } else {
      VM_WAIT(0);
    }
    SBAR; FENCE;
    bf16x8 af0[8], af1[8], b0[4], b1[4];
    // ---- kk0 ----
#pragma unroll
    for (int m = 0; m < 8; ++m)
      af0[m] = *(const bf16x8*)&sA[cb + baseA + m * 1024 + ch0 * 8];
#pragma unroll
    for (int n = 0; n < 4; ++n)
      b0[n] = *(const bf16x8*)&sB[cb + baseB + n * 1024 + ch0 * 8];
    PRIO_HI;
#pragma unroll
    for (int m = 0; m < 8; ++m)
#pragma unroll
      for (int n = 0; n < 4; ++n)
        acc[m][n] = mfma16(af0[m], b0[n], acc[m][n]);
    PRIO_LO;
    // ---- kk1 ----
#pragma unroll
    for (int m = 0; m < 8; ++m)
      af1[m] = *(const bf16x8*)&sA[cb + baseA + m * 1024 + ch1 * 8];
#pragma unroll
    for (int n = 0; n < 4; ++n)
      b1[n] = *(const bf16x8*)&sB[cb + baseB + n * 1024 + ch1 * 8];
    PRIO_HI;
#pragma unroll
    for (int m = 0; m < 8; ++m)
#pragma unroll
      for (int n = 0; n < 4; ++n)
        acc[m][n] = mfma16(af1[m], b1[n], acc[m][n]);
    PRIO_LO;
    FENCE; SBAR;
  }
  float gsig = 1.f / (1.f + __expf(-sgate[0]));
  int rbase = r0 + wr * 128 + l4 * 4;
  int cbase = n0 + wc * 64 + l15;
#pragma unroll
  for (int m = 0; m < 8; ++m) {
#pragma unroll
    for (int r = 0; r < 4; ++r) {
      int row = rbase + m * 16 + r;
      float wgt = (ex == 8) ? 1.f : lw[row];
      size_t srow_o = (size_t)row * HDIM;
#pragma unroll
      for (int n = 0; n < 4; ++n) {
        float o = clamp500(acc[m][n][r]);
        float val = (ex == 8) ? clamp500(o * gsig) : wgt * o;
        slot[srow_o + cbase + n * 16] = f2bf(val);
      }
    }
  }
}

// ---------------- combine: final = clamp(slot0 + slot1 + shared) ----------------
__global__ __launch_bounds__(256) void combine_kernel(
    const unsigned short* __restrict__ slot, const int* __restrict__ rowslot,
    const int* __restrict__ meta, float* __restrict__ out) {
  int i = blockIdx.x * 256 + threadIdx.x;  // 4-elem group index
  int t = i >> 8;
  int c = (i & 255) * 4;
  int sb = meta[16 + 8];
  int r0 = rowslot[2 * t], r1 = rowslot[2 * t + 1];
  ushort4 va = *(const ushort4*)(slot + (size_t)r0 * HDIM + c);
  ushort4 vb = *(const ushort4*)(slot + (size_t)r1 * HDIM + c);
  ushort4 vs = *(const ushort4*)(slot + (size_t)(sb + t) * HDIM + c);
  float4 o;
  o.x = clamp500(bf2f(va.x) + bf2f(vb.x) + bf2f(vs.x));
  o.y = clamp500(bf2f(va.y) + bf2f(vb.y) + bf2f(vs.y));
  o.z = clamp500(bf2f(va.z) + bf2f(vb.z) + bf2f(vs.z));
  o.w = clamp500(bf2f(va.w) + bf2f(vb.w) + bf2f(vs.w));
  *(float4*)(out + (size_t)t * HDIM + c) = o;
}

// ---------------- launch ----------------
extern "C" void kernel_launch(void* const* d_in, const int* in_sizes, int n_in,
                              void* d_out, int out_size, void* d_ws, size_t ws_size,
                              hipStream_t stream) {
  const float* x     = (const float*)d_in[0];
  const float* lnw   = (const float*)d_in[1];
  const float* lnb   = (const float*)d_in[2];
  const float* rw    = (const float*)d_in[3];
  const float* wg_f  = (const float*)d_in[4];
  const float* wu_f  = (const float*)d_in[5];
  const float* wd_f  = (const float*)d_in[6];
  const float* swg_f = (const float*)d_in[7];
  const float* swu_f = (const float*)d_in[8];
  const float* swd_f = (const float*)d_in[9];
  const float* sgate = (const float*)d_in[10];
  float* out = (float*)d_out;

  char* ws = (char*)d_ws;
  unsigned short* wgb = (unsigned short*)(ws + OFF_WG);
  unsigned short* wub = (unsigned short*)(ws + OFF_WU);
  unsigned short* wdb = (unsigned short*)(ws + OFF_WD);
  unsigned short* hf  = (unsigned short*)(ws + OFF_HF);
  unsigned short* P   = (unsigned short*)(ws + OFF_P);
  unsigned short* slot = (unsigned short*)(ws + OFF_SLOT);
  int*   top_i   = (int*)(ws + OFF_TOPI);
  float* top_w   = (float*)(ws + OFF_TOPW);
  int*   meta    = (int*)(ws + OFF_META);
  int*   ltok    = (int*)(ws + OFF_LTOK);
  float* lw      = (float*)(ws + OFF_LW);
  int*   rowslot = (int*)(ws + OFF_ROWS);
  float* part    = (float*)(ws + OFF_PART);

  hipFuncSetAttribute((const void*)gemm1_kernel,
                      hipFuncAttributeMaxDynamicSharedMemorySize, 131072);
  hipFuncSetAttribute((const void*)gemm2_kernel,
                      hipFuncAttributeMaxDynamicSharedMemorySize, 131072);

  // zero META (cursors) + LTOK + LW (pad-row init: token 0 / weight 0.0f)
  hipMemsetAsync(ws + OFF_META, 0, 4096ull + (size_t)ROWS_PAD * 8ull, stream);

  // router (blocks 0..1023, non-atomic per-block aux partials) runs
  // concurrently with fp32->bf16 wg/wu cvt (blocks 1024..3071).
  router_cvt_kernel<<<1024 + CVT_BLKS, 256, 0, stream>>>(
      x, lnw, lnb, rw, wg_f, wu_f, swg_f, swu_f,
      wgb, wub, hf, top_i, top_w, part);
  aux_kernel<<<1, 256, 0, stream>>>(top_i, part, meta, out + (size_t)TTOK * HDIM);
  scatter_kernel<<<32, 256, 0, stream>>>(top_i, top_w, meta, ltok, lw, rowslot);

  // gemm1 grid: y < MT_MAX = GEMM tiles; y >= MT_MAX = wd cvt role (overlaps
  // gemm1's tail; wdb complete before gemm2 starts via stream order).
  gemm1_kernel<<<dim3(16, MT_MAX + WDCVT_YBLKS), 512, 131072, stream>>>(
      hf, wgb, wub, wd_f, swd_f, wdb, P, meta, ltok);
  gemm2_kernel<<<dim3(4, MT_MAX), 512, 131072, stream>>>(P, wdb, slot, meta, lw, sgate);
  combine_kernel<<<TTOK * HDIM / 4 / 256, 256, 0, stream>>>(slot, rowslot, meta, out);
}

// Round 13
// 321.947 us; speedup vs baseline: 1.3539x; 1.0519x over previous
//
#include <hip/hip_runtime.h>
#include <hip/hip_bf16.h>
#include <cstdint>
#include <cstddef>

// ---------------- types ----------------
typedef __attribute__((ext_vector_type(8))) short bf16x8;
typedef __attribute__((ext_vector_type(4))) float f32x4;

#define HDIM 1024
#define IDIM 2048
#define TTOK 4096
#define NEXP 8
#define ROWS_PAD 14336          // 256-padded routed (<=10240) + shared 4096
#define MT_MAX 64               // max 256-row m-tiles: <=40 routed + 16 shared
#define EXP_W_ELEMS 2097152ull  // 2048*1024 elems per weight matrix per expert

// ---------------- workspace layout (bytes) ----------------
#define OFF_WG   0ull
#define OFF_WU   (OFF_WG + 9ull * EXP_W_ELEMS * 2ull)
#define OFF_WD   (OFF_WU + 9ull * EXP_W_ELEMS * 2ull)
#define OFF_HF   (OFF_WD + 9ull * EXP_W_ELEMS * 2ull)            // [4096][1024] bf16
#define OFF_P    (OFF_HF + 4096ull * 1024ull * 2ull)             // [ROWS_PAD][2048] bf16
#define OFF_SLOT (OFF_P  + (size_t)ROWS_PAD * 2048ull * 2ull)    // [ROWS_PAD][1024] bf16
#define OFF_TOPI (OFF_SLOT + (size_t)ROWS_PAD * 1024ull * 2ull)  // [8192] int
#define OFF_TOPW (OFF_TOPI + 8192ull * 4ull)                     // [8192] f32
#define OFF_META (OFF_TOPW + 8192ull * 4ull)                     // 4096B ints, see below
#define OFF_LTOK (OFF_META + 4096ull)                            // [ROWS_PAD] int
#define OFF_LW   (OFF_LTOK + (size_t)ROWS_PAD * 4ull)            // [ROWS_PAD] f32
#define OFF_ROWS (OFF_LW + (size_t)ROWS_PAD * 4ull)              // [8192] int
#define OFF_PART (OFF_ROWS + 8192ull * 4ull)                     // [1024][16] f32 partials

// meta (ints): [16..24]=256-padded base, [48]=ntiles256,
//              [64..127]=tile->expert, [128..191]=tile->row0.
// META + LTOK + LW zeroed by hipMemsetAsync (pad rows: token 0 / weight 0).
// part: no atomics — each router block owns part[blockIdx][0..9]
// (R10 lesson: ~18K same-line device atomics serialized ~85us).

#define VM_WAIT(n) asm volatile("s_waitcnt vmcnt(" #n ")" ::: "memory")
#define SBAR __builtin_amdgcn_s_barrier()
#define FENCE __builtin_amdgcn_sched_barrier(0)
#define PRIO_HI __builtin_amdgcn_s_setprio(1)
#define PRIO_LO __builtin_amdgcn_s_setprio(0)

__device__ __forceinline__ float clamp500(float v) {
  return fminf(fmaxf(v, -500.f), 500.f);
}

__device__ __forceinline__ unsigned short f2bf(float f) {
  unsigned int u = __float_as_uint(f);
  u += 0x7FFFu + ((u >> 16) & 1u);  // RNE; inputs always finite here
  return (unsigned short)(u >> 16);
}

__device__ __forceinline__ float bf2f(unsigned short u) {
  return __uint_as_float((unsigned)u << 16);
}

// async global->LDS, 16B per lane. LDS dest must be wave-uniform base + lane*16.
__device__ __forceinline__ void stage16(const unsigned short* g, unsigned short* l) {
  __builtin_amdgcn_global_load_lds(
      (const __attribute__((address_space(1))) void*)g,
      (__attribute__((address_space(3))) void*)l, 16, 0, 0);
}

__device__ __forceinline__ f32x4 mfma16(bf16x8 a, bf16x8 b, f32x4 c) {
  return __builtin_amdgcn_mfma_f32_16x16x32_bf16(a, b, c, 0, 0, 0);
}

__device__ __forceinline__ void cvt4(const float* __restrict__ src,
                                     unsigned short* __restrict__ dst, size_t j) {
  float4 f = ((const float4*)src)[j];
  uint2 pk;
  pk.x = (unsigned)f2bf(f.x) | ((unsigned)f2bf(f.y) << 16);
  pk.y = (unsigned)f2bf(f.z) | ((unsigned)f2bf(f.w) << 16);
  ((uint2*)dst)[j] = pk;
}

// ---------------- merged router + wg/wu weight-conversion kernel ----------------
// blocks [0,1024): one wave per token -> LN, logits, softmax, top2; per-block
// aux partials written NON-ATOMICALLY to part[blockIdx][0..9].
// blocks [1024,1024+CVT_BLKS): grid-stride fp32->bf16 convert of wg,wu.
// wd conversion rides inside gemm1's grid (only gemm2 needs it).
#define CVT_BLKS 3072
#define E4 (8ull * EXP_W_ELEMS / 4ull)   // float4s per big matrix (8 experts)
#define S4 (EXP_W_ELEMS / 4ull)          // float4s per shared matrix
__global__ __launch_bounds__(256) void router_cvt_kernel(
    const float* __restrict__ x, const float* __restrict__ lnw,
    const float* __restrict__ lnb, const float* __restrict__ rw,
    const float* __restrict__ wg_f, const float* __restrict__ wu_f,
    const float* __restrict__ swg_f, const float* __restrict__ swu_f,
    unsigned short* __restrict__ wgb, unsigned short* __restrict__ wub,
    unsigned short* __restrict__ hf, int* __restrict__ top_i,
    float* __restrict__ top_w, float* __restrict__ part) {
  if (blockIdx.x >= 1024) {
    // ---- cvt role: wg, swg, wu, swu ----
    size_t i = (size_t)(blockIdx.x - 1024) * 256 + threadIdx.x;
    const size_t stride = (size_t)CVT_BLKS * 256;
    const size_t n4 = 2 * (E4 + S4);
    for (; i < n4; i += stride) {
      size_t j = i;
      if (j < E4) { cvt4(wg_f, wgb, j); }
      else { j -= E4;
        if (j < S4) { cvt4(swg_f, wgb + 8 * EXP_W_ELEMS, j); }
        else { j -= S4;
          if (j < E4) { cvt4(wu_f, wub, j); }
          else { j -= E4; cvt4(swu_f, wub + 8 * EXP_W_ELEMS, j); }
        }
      }
    }
    return;
  }
  // ---- router role ----
  __shared__ float sred[4][10];
  int wv = threadIdx.x >> 6, lane = threadIdx.x & 63;
  int t = blockIdx.x * 4 + wv;
  const float4* xr = (const float4*)(x + (size_t)t * HDIM);
  float4 v[4];
  float s = 0.f;
#pragma unroll
  for (int j = 0; j < 4; ++j) {
    float4 f = xr[j * 64 + lane];
    f.x = clamp500(f.x); f.y = clamp500(f.y);
    f.z = clamp500(f.z); f.w = clamp500(f.w);
    v[j] = f;
    ushort4 hh;
    hh.x = f2bf(f.x); hh.y = f2bf(f.y); hh.z = f2bf(f.z); hh.w = f2bf(f.w);
    ((ushort4*)hf)[(size_t)t * 256 + j * 64 + lane] = hh;
    s += f.x + f.y + f.z + f.w;
  }
#pragma unroll
  for (int m = 32; m; m >>= 1) s += __shfl_xor(s, m);
  float mu = s * (1.f / HDIM);
  float s2 = 0.f;
#pragma unroll
  for (int j = 0; j < 4; ++j) {
    float4 d = v[j];
    d.x -= mu; d.y -= mu; d.z -= mu; d.w -= mu;
    s2 += d.x * d.x + d.y * d.y + d.z * d.z + d.w * d.w;
  }
#pragma unroll
  for (int m = 32; m; m >>= 1) s2 += __shfl_xor(s2, m);
  float rstd = rsqrtf(s2 * (1.f / HDIM) + 1e-5f);
  float acc[8];
#pragma unroll
  for (int e = 0; e < 8; ++e) acc[e] = 0.f;
#pragma unroll
  for (int j = 0; j < 4; ++j) {
    float4 w = ((const float4*)lnw)[j * 64 + lane];
    float4 b = ((const float4*)lnb)[j * 64 + lane];
    float4 hn;
    hn.x = fminf(fmaxf((v[j].x - mu) * rstd * w.x + b.x, -50.f), 50.f);
    hn.y = fminf(fmaxf((v[j].y - mu) * rstd * w.y + b.y, -50.f), 50.f);
    hn.z = fminf(fmaxf((v[j].z - mu) * rstd * w.z + b.z, -50.f), 50.f);
    hn.w = fminf(fmaxf((v[j].w - mu) * rstd * w.w + b.w, -50.f), 50.f);
#pragma unroll
    for (int e = 0; e < 8; ++e) {
      float4 r = ((const float4*)(rw + e * HDIM))[j * 64 + lane];
      acc[e] += hn.x * r.x + hn.y * r.y + hn.z * r.z + hn.w * r.w;
    }
  }
#pragma unroll
  for (int e = 0; e < 8; ++e) {
    float a = acc[e];
#pragma unroll
    for (int m = 32; m; m >>= 1) a += __shfl_xor(a, m);
    acc[e] = a;
  }
  if (lane == 0) {
    float lg[8], mx = -1e30f;
#pragma unroll
    for (int e = 0; e < 8; ++e) {
      float l = fminf(fmaxf(acc[e], -10.f), 10.f);
      lg[e] = l;
      mx = fmaxf(mx, l);
    }
    float se = 0.f;
    float ex[8];
#pragma unroll
    for (int e = 0; e < 8; ++e) { ex[e] = expf(lg[e] - mx); se += ex[e]; }
    float inv = 1.f / se;
    float pr[8];
#pragma unroll
    for (int e = 0; e < 8; ++e) {
      float p = ex[e] * inv;
      pr[e] = fminf(fmaxf(p, 1e-4f), 1.f);
      sred[wv][e] = pr[e];
    }
    int i0 = 0; float v0 = pr[0];
#pragma unroll
    for (int e = 1; e < 8; ++e) if (pr[e] > v0) { v0 = pr[e]; i0 = e; }
    int i1 = -1; float v1 = -1.f;
#pragma unroll
    for (int e = 0; e < 8; ++e) if (e != i0 && pr[e] > v1) { v1 = pr[e]; i1 = e; }
    float dsum = fmaxf(v0 + v1, 1e-4f);
    top_i[2 * t] = i0; top_i[2 * t + 1] = i1;
    top_w[2 * t] = v0 / dsum; top_w[2 * t + 1] = v1 / dsum;
    float lse = mx + logf(se);
    sred[wv][8] = lse * lse;
    float ent = 0.f;
#pragma unroll
    for (int e = 0; e < 8; ++e) {
      float ps = fminf(fmaxf(pr[e], 1e-4f), 1.f - 1e-4f);
      ent -= ps * logf(ps);
    }
    sred[wv][9] = ent;
  }
  __syncthreads();
  if (threadIdx.x < 10) {
    float sm = sred[0][threadIdx.x] + sred[1][threadIdx.x] +
               sred[2][threadIdx.x] + sred[3][threadIdx.x];
    part[blockIdx.x * 16 + threadIdx.x] = sm;   // private slot, no atomics
  }
}

// ---------------- aux loss + tile map + scatter (one 256-thread block) ----------------
// Deterministic output: slot contents are position-independent (rowslot tracks
// each token's slot), LDS-cursor ordering only permutes rows within an expert.
__global__ __launch_bounds__(256) void aux_scatter_kernel(
    const int* __restrict__ top_i, const float* __restrict__ top_w,
    const float* __restrict__ part, int* __restrict__ meta,
    int* __restrict__ ltok, float* __restrict__ lw,
    int* __restrict__ rowslot, float* __restrict__ aux_out) {
  __shared__ int sc[8];
  __shared__ int scur[8];
  __shared__ int sbase[9];
  __shared__ float red[256];
  __shared__ float sums[10];
  int tid = threadIdx.x;
  if (tid < 8) { sc[tid] = 0; scur[tid] = 0; }
  __syncthreads();
  for (int s = tid; s < 8192; s += 256) atomicAdd(&sc[top_i[s]], 1);
  for (int k = 0; k < 10; ++k) {
    float v = 0.f;
    for (int b = tid; b < 1024; b += 256) v += part[b * 16 + k];
    red[tid] = v;
    __syncthreads();
    for (int off = 128; off; off >>= 1) {
      if (tid < off) red[tid] += red[tid + off];
      __syncthreads();
    }
    if (tid == 0) sums[k] = red[0];
    __syncthreads();
  }
  if (tid == 0) {
    float lb = 0.f, usage = 0.f;
    for (int e = 0; e < 8; ++e) {
      float tpe = (float)sc[e] / 8192.f;
      float avg = sums[e] / 4096.f;
      lb += tpe * avg;
      usage += (tpe > 0.01f) ? 1.f : 0.f;
    }
    lb *= 8.f;
    float z_loss = (sums[8] / 4096.f) * 0.001f;
    float ent_loss = fmaxf(logf(8.f) - sums[9] / 4096.f, 0.f) * 0.01f;
    float util = (1.f - usage / 8.f) * 0.1f;
    *aux_out = fminf(fmaxf(lb + z_loss + ent_loss + util, 0.f), 10.f);
    // 256-padded tile map
    int base = 0, tct = 0;
    for (int e = 0; e < 8; ++e) {
      meta[16 + e] = base;
      sbase[e] = base;
      int nt = (sc[e] + 255) >> 8;
      for (int i = 0; i < nt; ++i) { meta[64 + tct] = e; meta[128 + tct] = base + i * 256; ++tct; }
      base += nt * 256;
    }
    meta[16 + 8] = base;      // shared padded base
    sbase[8] = base;
    for (int i = 0; i < 16; ++i) { meta[64 + tct] = 8; meta[128 + tct] = base + i * 256; ++tct; }
    meta[48] = tct;
  }
  __syncthreads();
  // scatter (pad entries already zeroed by launch-time memset)
  for (int s = tid; s < 8192; s += 256) {
    int e = top_i[s];
    int pos = atomicAdd(&scur[e], 1);
    int idx = sbase[e] + pos;
    ltok[idx] = s >> 1;
    lw[idx] = top_w[s];
    rowslot[s] = idx;
  }
  int sb = sbase[8];
  for (int s = tid; s < TTOK; s += 256) {
    ltok[sb + s] = s;
    lw[sb + s] = 1.f;
  }
}

// ---------------- GEMM1: P = clamp(silu(clamp(A*Wg^T)) * clamp(A*Wu^T)) ----------------
// BM=256, BN=128 (G and U), BK=64, 8 waves (2x4), bf16 via global_load_lds,
// vmcnt(8) pipeline (proven R4/R8 structure). Blocks with blockIdx.y >= MT_MAX
// take a wd fp32->bf16 cvt role instead (dispatched last -> overlaps gemm1's
// tail; gemm1 never reads wdb, gemm2 launches after, so no race).
#define WDCVT_YBLKS 16   // 16 x 16 = 256 cvt blocks x 512 thr
__global__ __launch_bounds__(512, 1) void gemm1_kernel(
    const unsigned short* __restrict__ hf,
    const unsigned short* __restrict__ wg_all,
    const unsigned short* __restrict__ wu_all,
    const float* __restrict__ wd_f, const float* __restrict__ swd_f,
    unsigned short* __restrict__ wdb,
    unsigned short* __restrict__ P,
    const int* __restrict__ meta, const int* __restrict__ ltok) {
  int mt = blockIdx.y, nt = blockIdx.x;
  if (mt >= MT_MAX) {
    // ---- wd cvt role ----
    size_t i = ((size_t)(mt - MT_MAX) * 16 + nt) * 512 + threadIdx.x;
    const size_t stride = (size_t)WDCVT_YBLKS * 16 * 512;
    const size_t n4 = E4 + S4;
    for (; i < n4; i += stride) {
      if (i < E4) cvt4(wd_f, wdb, i);
      else cvt4(swd_f, wdb + 8 * EXP_W_ELEMS, i - E4);
    }
    return;
  }
  if (mt >= meta[48]) return;
  int ex = meta[64 + mt];
  int r0 = meta[128 + mt];
  extern __shared__ unsigned short lds[];
  unsigned short* sA = lds;          // 2 x 16384 elems (256x64)
  unsigned short* sG = lds + 32768;  // 2 x 8192  (128x64)
  unsigned short* sU = lds + 49152;  // 2 x 8192
  int tid = threadIdx.x, lane = tid & 63, wv = tid >> 6;
  int wr = wv >> 2, wc = wv & 3;
  int l15 = lane & 15, l4 = lane >> 4;
  int srow = tid >> 3;              // staging row within a 64-row issue
  int gch = (tid & 7) ^ (srow & 7); // inverse-swizzled source 16B chunk
  int ldst = tid * 8;               // linear LDS dest elems within an issue
  const unsigned short* wg = wg_all + (size_t)ex * EXP_W_ELEMS;
  const unsigned short* wu = wu_all + (size_t)ex * EXP_W_ELEMS;
  int n0 = nt * 128;
  const unsigned short* srcA[4];
#pragma unroll
  for (int i = 0; i < 4; ++i) {
    int tok = ltok[r0 + i * 64 + srow];
    srcA[i] = hf + (size_t)tok * HDIM + gch * 8;
  }
  const unsigned short* srcG[2];
  const unsigned short* srcU[2];
#pragma unroll
  for (int i = 0; i < 2; ++i) {
    srcG[i] = wg + (size_t)(n0 + i * 64 + srow) * HDIM + gch * 8;
    srcU[i] = wu + (size_t)(n0 + i * 64 + srow) * HDIM + gch * 8;
  }
  // swizzled ds_read chunk per kk (row&7 == lane&7 for all frag rows)
  int ch0 = (0 + l4) ^ (lane & 7);
  int ch1 = (4 + l4) ^ (lane & 7);
  int baseA = (wr * 128 + l15) * 64;
  int baseG = (wc * 32 + l15) * 64;

  f32x4 zero = {0.f, 0.f, 0.f, 0.f};
  f32x4 accg[8][2], accu[8][2];
#pragma unroll
  for (int m = 0; m < 8; ++m)
#pragma unroll
    for (int n = 0; n < 2; ++n) { accg[m][n] = zero; accu[m][n] = zero; }

  // prologue: stage K-step 0 into buf0 (no wait here; t=0 top waits)
#pragma unroll
  for (int i = 0; i < 4; ++i) stage16(srcA[i], &sA[i * 4096 + ldst]);
#pragma unroll
  for (int i = 0; i < 2; ++i) stage16(srcG[i], &sG[i * 4096 + ldst]);
#pragma unroll
  for (int i = 0; i < 2; ++i) stage16(srcU[i], &sU[i * 4096 + ldst]);

  for (int t = 0; t < 16; ++t) {
    int cur = t & 1, nxt = cur ^ 1;
    int cbA = cur * 16384, cbG = cur * 8192;
    int nbA = nxt * 16384, nbG = nxt * 8192;
    if (t < 15) {
      int k1 = (t + 1) * 64;
      stage16(srcA[0] + k1, &sA[nbA + 0 * 4096 + ldst]);
      stage16(srcA[1] + k1, &sA[nbA + 1 * 4096 + ldst]);
      stage16(srcA[2] + k1, &sA[nbA + 2 * 4096 + ldst]);
      stage16(srcA[3] + k1, &sA[nbA + 3 * 4096 + ldst]);
      stage16(srcG[0] + k1, &sG[nbG + 0 * 4096 + ldst]);
      stage16(srcG[1] + k1, &sG[nbG + 1 * 4096 + ldst]);
      stage16(srcU[0] + k1, &sU[nbG + 0 * 4096 + ldst]);
      stage16(srcU[1] + k1, &sU[nbG + 1 * 4096 + ldst]);
      VM_WAIT(8);   // previous iter's 8 (buf cur) landed; these 8 stay in flight
    } else {
      VM_WAIT(0);
    }
    SBAR; FENCE;    // all waves' cur stages landed
    bf16x8 af0[8], af1[8], g0[2], g1[2], u0[2], u1[2];
    // ---- kk0 ----
#pragma unroll
    for (int m = 0; m < 8; ++m)
      af0[m] = *(const bf16x8*)&sA[cbA + baseA + m * 1024 + ch0 * 8];
#pragma unroll
    for (int n = 0; n < 2; ++n)
      g0[n] = *(const bf16x8*)&sG[cbG + baseG + n * 1024 + ch0 * 8];
    PRIO_HI;
#pragma unroll
    for (int m = 0; m < 8; ++m)
#pragma unroll
      for (int n = 0; n < 2; ++n)
        accg[m][n] = mfma16(af0[m], g0[n], accg[m][n]);
    PRIO_LO;
#pragma unroll
    for (int n = 0; n < 2; ++n)
      u0[n] = *(const bf16x8*)&sU[cbG + baseG + n * 1024 + ch0 * 8];
    PRIO_HI;
#pragma unroll
    for (int m = 0; m < 8; ++m)
#pragma unroll
      for (int n = 0; n < 2; ++n)
        accu[m][n] = mfma16(af0[m], u0[n], accu[m][n]);
    PRIO_LO;
    // ---- kk1 ----
#pragma unroll
    for (int m = 0; m < 8; ++m)
      af1[m] = *(const bf16x8*)&sA[cbA + baseA + m * 1024 + ch1 * 8];
#pragma unroll
    for (int n = 0; n < 2; ++n)
      g1[n] = *(const bf16x8*)&sG[cbG + baseG + n * 1024 + ch1 * 8];
    PRIO_HI;
#pragma unroll
    for (int m = 0; m < 8; ++m)
#pragma unroll
      for (int n = 0; n < 2; ++n)
        accg[m][n] = mfma16(af1[m], g1[n], accg[m][n]);
    PRIO_LO;
#pragma unroll
    for (int n = 0; n < 2; ++n)
      u1[n] = *(const bf16x8*)&sU[cbG + baseG + n * 1024 + ch1 * 8];
    PRIO_HI;
#pragma unroll
    for (int m = 0; m < 8; ++m)
#pragma unroll
      for (int n = 0; n < 2; ++n)
        accu[m][n] = mfma16(af1[m], u1[n], accu[m][n]);
    PRIO_LO;
    FENCE; SBAR;    // all waves done reading cur before t+1 overwrites it
  }
  // epilogue: SwiGLU, write bf16 P (padded rows junk, never read)
  int rbase = r0 + wr * 128 + l4 * 4;
  int cbase = n0 + wc * 32 + l15;
#pragma unroll
  for (int m = 0; m < 8; ++m) {
#pragma unroll
    for (int r = 0; r < 4; ++r) {
      size_t prow = (size_t)(rbase + m * 16 + r) * IDIM;
#pragma unroll
      for (int n = 0; n < 2; ++n) {
        float g = clamp500(accg[m][n][r]);
        float u = clamp500(accu[m][n][r]);
        float sl = g / (1.f + __expf(-g));
        float p = clamp500(sl * u);
        P[prow + cbase + n * 16] = f2bf(p);
      }
    }
  }
}

// ---------------- GEMM2: slot = weight * clamp(P*Wd^T)  (shared: clamp(clamp(.)*sig)) ----------------
// BM=256, BN=256, BK=64, 8 waves (2x4), vmcnt(8) pipeline (proven R8 structure).
__global__ __launch_bounds__(512, 1) void gemm2_kernel(
    const unsigned short* __restrict__ P,
    const unsigned short* __restrict__ wd_all,
    unsigned short* __restrict__ slot,
    const int* __restrict__ meta, const float* __restrict__ lw,
    const float* __restrict__ sgate) {
  int mt = blockIdx.y, nt = blockIdx.x;
  if (mt >= meta[48]) return;
  int ex = meta[64 + mt];
  int r0 = meta[128 + mt];
  extern __shared__ unsigned short lds[];
  unsigned short* sA = lds;          // 2 x 16384 (256x64)
  unsigned short* sB = lds + 32768;  // 2 x 16384 (256x64)
  int tid = threadIdx.x, lane = tid & 63, wv = tid >> 6;
  int wr = wv >> 2, wc = wv & 3;
  int l15 = lane & 15, l4 = lane >> 4;
  int srow = tid >> 3;
  int gch = (tid & 7) ^ (srow & 7);
  int ldst = tid * 8;
  const unsigned short* wd = wd_all + (size_t)ex * EXP_W_ELEMS;
  int n0 = nt * 256;
  const unsigned short* srcA[4];
  const unsigned short* srcB[4];
#pragma unroll
  for (int i = 0; i < 4; ++i) {
    srcA[i] = P + (size_t)(r0 + i * 64 + srow) * IDIM + gch * 8;
    srcB[i] = wd + (size_t)(n0 + i * 64 + srow) * IDIM + gch * 8;
  }
  int ch0 = (0 + l4) ^ (lane & 7);
  int ch1 = (4 + l4) ^ (lane & 7);
  int baseA = (wr * 128 + l15) * 64;
  int baseB = (wc * 64 + l15) * 64;

  f32x4 zero = {0.f, 0.f, 0.f, 0.f};
  f32x4 acc[8][4];
#pragma unroll
  for (int m = 0; m < 8; ++m)
#pragma unroll
    for (int n = 0; n < 4; ++n) acc[m][n] = zero;

  // prologue
#pragma unroll
  for (int i = 0; i < 4; ++i) stage16(srcA[i], &sA[i * 4096 + ldst]);
#pragma unroll
  for (int i = 0; i < 4; ++i) stage16(srcB[i], &sB[i * 4096 + ldst]);

  for (int t = 0; t < 32; ++t) {
    int cur = t & 1, nxt = cur ^ 1;
    int cb = cur * 16384, nb = nxt * 16384;
    if (t < 31) {
      int k1 = (t + 1) * 64;
      stage16(srcA[0] + k1, &sA[nb + 0 * 4096 + ldst]);
      stage16(srcA[1] + k1, &sA[nb + 1 * 4096 + ldst]);
      stage16(srcA[2] + k1, &sA[nb + 2 * 4096 + ldst]);
      stage16(srcA[3] + k1, &sA[nb + 3 * 4096 + ldst]);
      stage16(srcB[0] + k1, &sB[nb + 0 * 4096 + ldst]);
      stage16(srcB[1] + k1, &sB[nb + 1 * 4096 + ldst]);
      stage16(srcB[2] + k1, &sB[nb + 2 * 4096 + ldst]);
      stage16(srcB[3] + k1, &sB[nb + 3 * 4096 + ldst]);
      VM_WAIT(8);
    } else {
      VM_WAIT(0);
    }
    SBAR; FENCE;
    bf16x8 af0[8], af1[8], b0[4], b1[4];
    // ---- kk0 ----
#pragma unroll
    for (int m = 0; m < 8; ++m)
      af0[m] = *(const bf16x8*)&sA[cb + baseA + m * 1024 + ch0 * 8];
#pragma unroll
    for (int n = 0; n < 4; ++n)
      b0[n] = *(const bf16x8*)&sB[cb + baseB + n * 1024 + ch0 * 8];
    PRIO_HI;
#pragma unroll
    for (int m = 0; m < 8; ++m)
#pragma unroll
      for (int n = 0; n < 4; ++n)
        acc[m][n] = mfma16(af0[m], b0[n], acc[m][n]);
    PRIO_LO;
    // ---- kk1 ----
#pragma unroll
    for (int m = 0; m < 8; ++m)
      af1[m] = *(const bf16x8*)&sA[cb + baseA + m * 1024 + ch1 * 8];
#pragma unroll
    for (int n = 0; n < 4; ++n)
      b1[n] = *(const bf16x8*)&sB[cb + baseB + n * 1024 + ch1 * 8];
    PRIO_HI;
#pragma unroll
    for (int m = 0; m < 8; ++m)
#pragma unroll
      for (int n = 0; n < 4; ++n)
        acc[m][n] = mfma16(af1[m], b1[n], acc[m][n]);
    PRIO_LO;
    FENCE; SBAR;
  }
  float gsig = 1.f / (1.f + __expf(-sgate[0]));
  int rbase = r0 + wr * 128 + l4 * 4;
  int cbase = n0 + wc * 64 + l15;
#pragma unroll
  for (int m = 0; m < 8; ++m) {
#pragma unroll
    for (int r = 0; r < 4; ++r) {
      int row = rbase + m * 16 + r;
      float wgt = (ex == 8) ? 1.f : lw[row];
      size_t srow_o = (size_t)row * HDIM;
#pragma unroll
      for (int n = 0; n < 4; ++n) {
        float o = clamp500(acc[m][n][r]);
        float val = (ex == 8) ? clamp500(o * gsig) : wgt * o;
        slot[srow_o + cbase + n * 16] = f2bf(val);
      }
    }
  }
}

// ---------------- combine: final = clamp(slot0 + slot1 + shared) ----------------
__global__ __launch_bounds__(256) void combine_kernel(
    const unsigned short* __restrict__ slot, const int* __restrict__ rowslot,
    const int* __restrict__ meta, float* __restrict__ out) {
  int i = blockIdx.x * 256 + threadIdx.x;  // 4-elem group index
  int t = i >> 8;
  int c = (i & 255) * 4;
  int sb = meta[16 + 8];
  int r0 = rowslot[2 * t], r1 = rowslot[2 * t + 1];
  ushort4 va = *(const ushort4*)(slot + (size_t)r0 * HDIM + c);
  ushort4 vb = *(const ushort4*)(slot + (size_t)r1 * HDIM + c);
  ushort4 vs = *(const ushort4*)(slot + (size_t)(sb + t) * HDIM + c);
  float4 o;
  o.x = clamp500(bf2f(va.x) + bf2f(vb.x) + bf2f(vs.x));
  o.y = clamp500(bf2f(va.y) + bf2f(vb.y) + bf2f(vs.y));
  o.z = clamp500(bf2f(va.z) + bf2f(vb.z) + bf2f(vs.z));
  o.w = clamp500(bf2f(va.w) + bf2f(vb.w) + bf2f(vs.w));
  *(float4*)(out + (size_t)t * HDIM + c) = o;
}

// ---------------- launch ----------------
extern "C" void kernel_launch(void* const* d_in, const int* in_sizes, int n_in,
                              void* d_out, int out_size, void* d_ws, size_t ws_size,
                              hipStream_t stream) {
  const float* x     = (const float*)d_in[0];
  const float* lnw   = (const float*)d_in[1];
  const float* lnb   = (const float*)d_in[2];
  const float* rw    = (const float*)d_in[3];
  const float* wg_f  = (const float*)d_in[4];
  const float* wu_f  = (const float*)d_in[5];
  const float* wd_f  = (const float*)d_in[6];
  const float* swg_f = (const float*)d_in[7];
  const float* swu_f = (const float*)d_in[8];
  const float* swd_f = (const float*)d_in[9];
  const float* sgate = (const float*)d_in[10];
  float* out = (float*)d_out;

  char* ws = (char*)d_ws;
  unsigned short* wgb = (unsigned short*)(ws + OFF_WG);
  unsigned short* wub = (unsigned short*)(ws + OFF_WU);
  unsigned short* wdb = (unsigned short*)(ws + OFF_WD);
  unsigned short* hf  = (unsigned short*)(ws + OFF_HF);
  unsigned short* P   = (unsigned short*)(ws + OFF_P);
  unsigned short* slot = (unsigned short*)(ws + OFF_SLOT);
  int*   top_i   = (int*)(ws + OFF_TOPI);
  float* top_w   = (float*)(ws + OFF_TOPW);
  int*   meta    = (int*)(ws + OFF_META);
  int*   ltok    = (int*)(ws + OFF_LTOK);
  float* lw      = (float*)(ws + OFF_LW);
  int*   rowslot = (int*)(ws + OFF_ROWS);
  float* part    = (float*)(ws + OFF_PART);

  hipFuncSetAttribute((const void*)gemm1_kernel,
                      hipFuncAttributeMaxDynamicSharedMemorySize, 131072);
  hipFuncSetAttribute((const void*)gemm2_kernel,
                      hipFuncAttributeMaxDynamicSharedMemorySize, 131072);

  // zero META + LTOK + LW (pad-row init: token 0 / weight 0.0f)
  hipMemsetAsync(ws + OFF_META, 0, 4096ull + (size_t)ROWS_PAD * 8ull, stream);

  // router (blocks 0..1023, non-atomic per-block aux partials) runs
  // concurrently with fp32->bf16 wg/wu cvt (blocks 1024..4095).
  router_cvt_kernel<<<1024 + CVT_BLKS, 256, 0, stream>>>(
      x, lnw, lnb, rw, wg_f, wu_f, swg_f, swu_f,
      wgb, wub, hf, top_i, top_w, part);
  aux_scatter_kernel<<<1, 256, 0, stream>>>(
      top_i, top_w, part, meta, ltok, lw, rowslot, out + (size_t)TTOK * HDIM);

  // gemm1 grid: y < MT_MAX = GEMM tiles; y >= MT_MAX = wd cvt role (overlaps
  // gemm1's tail; wdb complete before gemm2 starts via stream order).
  gemm1_kernel<<<dim3(16, MT_MAX + WDCVT_YBLKS), 512, 131072, stream>>>(
      hf, wgb, wub, wd_f, swd_f, wdb, P, meta, ltok);
  gemm2_kernel<<<dim3(4, MT_MAX), 512, 131072, stream>>>(P, wdb, slot, meta, lw, sgate);
  combine_kernel<<<TTOK * HDIM / 4 / 256, 256, 0, stream>>>(slot, rowslot, meta, out);
}